// Round 1
// baseline (728.325 us; speedup 1.0000x reference)
//
#include <hip/hip_runtime.h>
#include <hip/hip_bf16.h>

#define L_ 4096
#define D_ 1024
#define H_ 16
#define HD_ 64
#define NW_ 8
#define WIN_ 512
#define TD (3*D_)

typedef __attribute__((ext_vector_type(8))) short bf16x8;
typedef __attribute__((ext_vector_type(4))) float f32x4;

typedef __attribute__((address_space(1))) const void GVp;
typedef __attribute__((address_space(3))) void LVp;

__device__ __forceinline__ f32x4 mfma16(bf16x8 a, bf16x8 b, f32x4 c) {
    return __builtin_amdgcn_mfma_f32_16x16x32_bf16(a, b, c, 0, 0, 0);
}

__device__ __forceinline__ short f2bfs(float f) {
    __hip_bfloat16 h = __float2bfloat16(f);
    return *reinterpret_cast<short*>(&h);
}

__device__ __forceinline__ float lclamp(float v, float c) {
    return fminf(fmaxf(v, -c), c);
}

// rotary additive term for (seq pos l, feature d), exact fp32
__device__ __forceinline__ float rot_add(const float* rf, int l, int d) {
    const int j = d & 511;
    const float r = rf[j];
    const float inv = exp2f((float)j * 0.02595256324130752f); // 10000^(j/512)
    const float ang = r * (float)l / inv;
    return (d < 512) ? cosf(ang) : sinf(ang);
}

// ---------------------------------------------------------------------------
__global__ __launch_bounds__(256) void rotary_k(
    const float* __restrict__ x,
    const float* __restrict__ rf,
    __hip_bfloat16* __restrict__ x1b)
{
    const int idx = blockIdx.x * 256 + threadIdx.x;   // over L*D
    const int l = idx >> 10;
    const int d = idx & 1023;
    const float v = x[idx] + rot_add(rf, l, d);
    x1b[idx] = __float2bfloat16(lclamp(v, 1.0e4f));
}

// ---------------------------------------------------------------------------
// C[M,N] = A[M,1024](bf16) @ W[N,1024]^T(fp32->bf16) + bias[N](fp32)
//          (+ residual), out bf16 (Cb) or fp32 (Cf).
// Double-buffered LDS, ONE raw barrier per BK=32 step.
// Key change vs prev: __syncthreads() -> s_waitcnt lgkmcnt(0) + raw s_barrier,
// so the global loads issued at step i stay IN FLIGHT across the barrier and
// are only waited on (via register data-dependence) at writeLDS in step i+1
// (T4: never drain vmcnt in the main loop). Plus XCD-aware n-major block
// swizzle so each XCD's L2 keeps its W panels resident (T1).
// ---------------------------------------------------------------------------
__global__ __launch_bounds__(256) void gemm_bt(
    const __hip_bfloat16* __restrict__ A,
    const float* __restrict__ Wt,
    const float* __restrict__ bias,
    const float* __restrict__ xin,
    const float* __restrict__ rf,
    int residMode,
    __hip_bfloat16* __restrict__ Cb,
    float* __restrict__ Cf,
    int N, int wStrideW, int wStrideB)
{
    const int K = D_;

    // XCD-aware bijective swizzle (grids here are always divisible by 8):
    // n-major chunks -> each XCD owns a few n-panels of W (L2-resident).
    int bn = blockIdx.x, bm = blockIdx.y;
    {
        const int gx = gridDim.x, gy = gridDim.y;
        const int nblk = gx * gy;
        if ((nblk & 7) == 0) {
            const int lid = blockIdx.y * gx + blockIdx.x;
            const int per = nblk >> 3;
            const int t = (lid & 7) * per + (lid >> 3);
            bn = t / gy;
            bm = t - bn * gy;
        }
    }
    const int m0 = bm * 128;
    const int n0 = bn * 128;
    const int win = m0 / WIN_;
    const float* Wp = Wt + (size_t)win * (size_t)wStrideW;
    const float* Bp = bias + (size_t)win * (size_t)wStrideB;

    __shared__ __align__(16) short As[2][128 * 40];
    __shared__ __align__(16) short Bs[2][128 * 40];

    const int tid  = threadIdx.x;
    const int lane = tid & 63;
    const int wave = tid >> 6;
    const int wm = (wave & 1) * 64;
    const int wn = (wave >> 1) * 64;
    const int lrow = lane & 15;
    const int kg   = lane >> 4;

    // staging: each thread covers (row0,part) and (row0+64,part)
    const int row0 = tid >> 2;
    const int part = tid & 3;
    const size_t aoff0 = (size_t)(m0 + row0) * K + part * 8;
    const size_t aoff1 = (size_t)(m0 + row0 + 64) * K + part * 8;
    const size_t woff0 = (size_t)(n0 + row0) * K + part * 8;
    const size_t woff1 = (size_t)(n0 + row0 + 64) * K + part * 8;

    uint4 ar[2];
    float4 wr[4];
    auto loadRegs = [&](int k0) {
        ar[0] = *(const uint4*)&A[aoff0 + k0];
        ar[1] = *(const uint4*)&A[aoff1 + k0];
        wr[0] = *(const float4*)&Wp[woff0 + k0];
        wr[1] = *(const float4*)&Wp[woff0 + k0 + 4];
        wr[2] = *(const float4*)&Wp[woff1 + k0];
        wr[3] = *(const float4*)&Wp[woff1 + k0 + 4];
    };
    auto writeLDS = [&](int b) {
        *(uint4*)&As[b][row0 * 40 + part * 8] = ar[0];
        *(uint4*)&As[b][(row0 + 64) * 40 + part * 8] = ar[1];
        short t0[8], t1[8];
        t0[0]=f2bfs(wr[0].x); t0[1]=f2bfs(wr[0].y); t0[2]=f2bfs(wr[0].z); t0[3]=f2bfs(wr[0].w);
        t0[4]=f2bfs(wr[1].x); t0[5]=f2bfs(wr[1].y); t0[6]=f2bfs(wr[1].z); t0[7]=f2bfs(wr[1].w);
        t1[0]=f2bfs(wr[2].x); t1[1]=f2bfs(wr[2].y); t1[2]=f2bfs(wr[2].z); t1[3]=f2bfs(wr[2].w);
        t1[4]=f2bfs(wr[3].x); t1[5]=f2bfs(wr[3].y); t1[6]=f2bfs(wr[3].z); t1[7]=f2bfs(wr[3].w);
        *(uint4*)&Bs[b][row0 * 40 + part * 8] = *(uint4*)t0;
        *(uint4*)&Bs[b][(row0 + 64) * 40 + part * 8] = *(uint4*)t1;
    };

    const f32x4 zero4 = {0.f, 0.f, 0.f, 0.f};
    f32x4 acc[4][4];
    #pragma unroll
    for (int i = 0; i < 4; i++)
        #pragma unroll
        for (int jj = 0; jj < 4; jj++) acc[i][jj] = zero4;

    const int nsteps = K / 32;            // 32
    loadRegs(0);
    writeLDS(0);
    loadRegs(32);

    for (int i = 0; i < nsteps; i++) {
        // LDS ordering only; vmcnt stays un-drained (loads remain in flight).
        asm volatile("s_waitcnt lgkmcnt(0)" ::: "memory");
        __builtin_amdgcn_s_barrier();
        const int cur = i & 1;
        bf16x8 af[4], bfr[4];
        #pragma unroll
        for (int ii = 0; ii < 4; ii++)
            af[ii] = *(const bf16x8*)&As[cur][(wm + ii * 16 + lrow) * 40 + kg * 8];
        #pragma unroll
        for (int jj = 0; jj < 4; jj++)
            bfr[jj] = *(const bf16x8*)&Bs[cur][(wn + jj * 16 + lrow) * 40 + kg * 8];
        #pragma unroll
        for (int ii = 0; ii < 4; ii++)
            #pragma unroll
            for (int jj = 0; jj < 4; jj++)
                acc[ii][jj] = mfma16(af[ii], bfr[jj], acc[ii][jj]);
        if (i + 1 < nsteps) {
            writeLDS(1 - cur);            // waits (vmcnt) on k(i+1) loads only here
            if (i + 2 < nsteps) loadRegs((i + 2) * 32);
        }
    }

    // C/D layout: row = kg*4 + r, col = lrow  (within each 16x16 tile)
    #pragma unroll
    for (int jj = 0; jj < 4; jj++) {
        const int col = n0 + wn + jj * 16 + lrow;
        const float bv = Bp[col];
        #pragma unroll
        for (int i = 0; i < 4; i++) {
            #pragma unroll
            for (int r = 0; r < 4; r++) {
                const int row = m0 + wm + i * 16 + kg * 4 + r;
                float v = acc[i][jj][r] + bv;
                if (residMode) {
                    v += xin[(size_t)row * D_ + col] + rot_add(rf, row, col);
                }
                v = lclamp(v, 1.0e4f);
                if (Cf) Cf[(size_t)row * N + col] = v;
                else    Cb[(size_t)row * N + col] = __float2bfloat16(v);
            }
        }
    }
}

// ---------------------------------------------------------------------------
// Transpose V out of qkv: Vt[h][vd][l] = qkv[l][2*D + h*64 + vd]
// ---------------------------------------------------------------------------
__global__ __launch_bounds__(256) void transpose_v(
    const __hip_bfloat16* __restrict__ qkv,
    __hip_bfloat16* __restrict__ Vt)
{
    __shared__ __align__(16) short Ts[64 * 72];
    const int t = threadIdx.x;
    const int l0 = blockIdx.x * 64;
    const int h = blockIdx.y;
    #pragma unroll
    for (int p = 0; p < 2; p++) {
        const int idx = p * 256 + t;
        const int key = idx >> 3, part = idx & 7;
        *(uint4*)&Ts[key * 72 + part * 8] =
            *(const uint4*)&qkv[(size_t)(l0 + key) * TD + 2 * D_ + h * HD_ + part * 8];
    }
    __syncthreads();
    #pragma unroll
    for (int p = 0; p < 2; p++) {
        const int idx = p * 256 + t;
        const int vd = idx >> 3, part = idx & 7;
        short tmp[8];
        #pragma unroll
        for (int j = 0; j < 8; j++) tmp[j] = Ts[(part * 8 + j) * 72 + vd];
        *(uint4*)&Vt[(size_t)(h * HD_ + vd) * L_ + l0 + part * 8] = *(uint4*)tmp;
    }
}

// ---------------------------------------------------------------------------
// Flash attention v4: fixed-max streaming softmax (M=16). Scores bounded
// (|0.125*s| << 16); p = exp2(s*0.125*log2e - 16*log2e). No per-tile
// shuffle reductions, no alpha rescale; row-sum reduced once at the end.
// K/V staged via double-buffered global_load_lds with XOR-8 source swizzle.
// XCD-aware block swizzle: each XCD owns whole heads -> K/V L2-resident.
// ---------------------------------------------------------------------------
__global__ __launch_bounds__(256, 3) void attn_k(
    const __hip_bfloat16* __restrict__ qkv,
    const __hip_bfloat16* __restrict__ Vt,
    __hip_bfloat16* __restrict__ o,
    int Sw)
{
    const int tid  = threadIdx.x;
    const int lane = tid & 63;
    const int wave = tid >> 6;
    const int lrow = lane & 15;
    const int kg   = lane >> 4;

    // XCD swizzle of (x, y, z): consecutive per-XCD tiles share (head, window)
    int bx = blockIdx.x, by = blockIdx.y, bz = blockIdx.z;
    {
        const int gx = gridDim.x, gy = gridDim.y, gz = gridDim.z;
        const int nblk = gx * gy * gz;
        if ((nblk & 7) == 0) {
            const int lid = (blockIdx.z * gy + blockIdx.y) * gx + blockIdx.x;
            const int per = nblk >> 3;
            const int t = (lid & 7) * per + (lid >> 3);
            bx = t % gx;
            const int rest = t / gx;
            by = rest % gy;
            bz = rest / gy;
        }
    }
    const int h = by;
    const int wbase = bz * Sw;
    const int q0 = wbase + bx * 64 + wave * 16;

    const short* Kglb = reinterpret_cast<const short*>(qkv)
                        + (size_t)wbase * TD + D_ + h * HD_;
    const short* Vtglb = reinterpret_cast<const short*>(Vt)
                         + (size_t)h * HD_ * L_ + wbase;
    const __hip_bfloat16* Q = qkv + (size_t)q0 * TD + h * HD_;

    __shared__ __align__(16) short Ks[2][64 * 64];
    __shared__ __align__(16) short Vs[2][64 * 64];
    __shared__ __align__(16) short Ps[4][16 * 72];
    short* myP = &Ps[wave][0];

    const bf16x8 qf0 = *(const bf16x8*)&Q[(size_t)lrow * TD + kg * 8];
    const bf16x8 qf1 = *(const bf16x8*)&Q[(size_t)lrow * TD + 32 + kg * 8];

    const f32x4 zero4 = {0.f, 0.f, 0.f, 0.f};
    float lacc[4];
    f32x4 oacc[4];
    #pragma unroll
    for (int r = 0; r < 4; r++) lacc[r] = 0.f;
    #pragma unroll
    for (int t = 0; t < 4; t++) oacc[t] = zero4;

    auto stage = [&](int c, int buf) {
        const int s0 = (wave & 1) * 256;
        if (wave < 2) {
            #pragma unroll
            for (int j = 0; j < 4; j++) {
                const int s = s0 + j * 64 + lane;
                const int r = s >> 3;
                const int cb = (s & 7) ^ (r & 7);
                const short* src = Kglb + (size_t)(c + r) * TD + cb * 8;
                __builtin_amdgcn_global_load_lds(
                    (GVp*)src, (LVp*)&Ks[buf][(s0 + j * 64) * 8], 16, 0, 0);
            }
        } else {
            #pragma unroll
            for (int j = 0; j < 4; j++) {
                const int s = s0 + j * 64 + lane;
                const int r = s >> 3;
                const int cb = (s & 7) ^ (r & 7);
                const short* src = Vtglb + (size_t)r * L_ + c + cb * 8;
                __builtin_amdgcn_global_load_lds(
                    (GVp*)src, (LVp*)&Vs[buf][(s0 + j * 64) * 8], 16, 0, 0);
            }
        }
    };

    const int ntiles = Sw >> 6;
    stage(0, 0);

    // p = exp2(fma(s, 0.125*log2e, -16*log2e))
    const float SC = 0.18033688011112042f;
    const float MB = -23.083120654223414f;

    for (int i = 0; i < ntiles; i++) {
        const int cur = i & 1;
        __syncthreads();
        if (i + 1 < ntiles) stage((i + 1) << 6, 1 - cur);

        const short* Kl = Ks[cur];
        const short* Vl = Vs[cur];
        const int sw = lrow & 7;

        f32x4 s[4];
        #pragma unroll
        for (int kt = 0; kt < 4; kt++) {
            const int key = kt * 16 + lrow;
            bf16x8 k0 = *(const bf16x8*)&Kl[key * 64 + ((kg     ^ sw) * 8)];
            bf16x8 k1 = *(const bf16x8*)&Kl[key * 64 + (((kg+4) ^ sw) * 8)];
            f32x4 acc = zero4;
            acc = mfma16(qf0, k0, acc);
            acc = mfma16(qf1, k1, acc);
            s[kt] = acc;
        }

        asm volatile("" ::: "memory");
        #pragma unroll
        for (int kt = 0; kt < 4; kt++) {
            #pragma unroll
            for (int r = 0; r < 4; r++) {
                const float p = exp2f(fmaf(s[kt][r], SC, MB));
                lacc[r] += p;
                myP[(kg * 4 + r) * 72 + kt * 16 + lrow] = f2bfs(p);
            }
        }
        asm volatile("s_waitcnt lgkmcnt(0)" ::: "memory");
        const bf16x8 pf0 = *(const bf16x8*)&myP[lrow * 72 + kg * 8];
        const bf16x8 pf1 = *(const bf16x8*)&myP[lrow * 72 + 32 + kg * 8];

        #pragma unroll
        for (int t = 0; t < 4; t++) {
            const int vd = t * 16 + lrow;
            bf16x8 v0 = *(const bf16x8*)&Vl[vd * 64 + ((kg     ^ sw) * 8)];
            bf16x8 v1 = *(const bf16x8*)&Vl[vd * 64 + (((kg+4) ^ sw) * 8)];
            oacc[t] = mfma16(pf0, v0, oacc[t]);
            oacc[t] = mfma16(pf1, v1, oacc[t]);
        }
    }

    // reduce row-sums across the 16 lanes sharing each row (lrow axis)
    #pragma unroll
    for (int off = 1; off < 16; off <<= 1)
        #pragma unroll
        for (int r = 0; r < 4; r++)
            lacc[r] += __shfl_xor(lacc[r], off, 64);

    #pragma unroll
    for (int t = 0; t < 4; t++) {
        #pragma unroll
        for (int r = 0; r < 4; r++) {
            const int row = q0 + kg * 4 + r;
            const int col = h * HD_ + t * 16 + lrow;
            o[(size_t)row * D_ + col] =
                __float2bfloat16(lclamp(oacc[t][r] / lacc[r], 1.0e4f));
        }
    }
}

// ---------------------------------------------------------------------------
extern "C" void kernel_launch(void* const* d_in, const int* in_sizes, int n_in,
                              void* d_out, int out_size, void* d_ws, size_t ws_size,
                              hipStream_t stream)
{
    const float* x   = (const float*)d_in[0];
    const float* rf  = (const float*)d_in[1];
    const float* wwi = (const float*)d_in[2];
    const float* wbi = (const float*)d_in[3];
    const float* wwo = (const float*)d_in[4];
    const float* wbo = (const float*)d_in[5];
    const float* fwi = (const float*)d_in[6];
    const float* fbi = (const float*)d_in[7];
    const float* fwo = (const float*)d_in[8];
    const float* fbo = (const float*)d_in[9];

    // ws: 32 MiB (qkv 24 + ob 8). d_out's first 8 MiB time-shared between
    // xsc (x1/x2 bf16) and Vt — live ranges sequential on stream.
    char* ws = (char*)d_ws;
    __hip_bfloat16* qkv = (__hip_bfloat16*)(ws);                 // [L,3D] 24 MiB
    __hip_bfloat16* ob  = (__hip_bfloat16*)(ws + (24u << 20));   // [L,D]   8 MiB
    __hip_bfloat16* xsc = (__hip_bfloat16*)d_out;                // [L,D] bf16 scratch
    __hip_bfloat16* Vt  = (__hip_bfloat16*)d_out;                // [H,HD,L] bf16

    // 1. rotary add -> x1 (bf16)
    rotary_k<<<dim3(L_ * D_ / 256), 256, 0, stream>>>(x, rf, xsc);

    // 2. per-window qkv = x1 @ win_w_in^T + win_b_in
    gemm_bt<<<dim3(TD / 128, L_ / 128), 256, 0, stream>>>(
        xsc, wwi, wbi, nullptr, nullptr, 0, qkv, nullptr, TD, TD * D_, TD);

    // 2b. V transpose
    transpose_v<<<dim3(L_ / 64, H_), 256, 0, stream>>>(qkv, Vt);

    // 3. windowed attention (Sw = 512)
    attn_k<<<dim3(WIN_ / 64, H_, NW_), 256, 0, stream>>>(qkv, Vt, ob, WIN_);

    // 4. x2 = (x + rotary, exact fp32) + o @ win_w_out^T + win_b_out
    gemm_bt<<<dim3(D_ / 128, L_ / 128), 256, 0, stream>>>(
        ob, wwo, wbo, x, rf, 1, xsc, nullptr, D_, D_ * D_, D_);

    // 5. final qkv = x2 @ fin_w_in^T + fin_b_in
    gemm_bt<<<dim3(TD / 128, L_ / 128), 256, 0, stream>>>(
        xsc, fwi, fbi, nullptr, nullptr, 0, qkv, nullptr, TD, 0, 0);

    // 5b. V transpose
    transpose_v<<<dim3(L_ / 64, H_), 256, 0, stream>>>(qkv, Vt);

    // 6. global attention (Sw = 4096)
    attn_k<<<dim3(L_ / 64, H_, 1), 256, 0, stream>>>(qkv, Vt, ob, L_);

    // 7. out = o @ fin_w_out^T + fin_b_out  -> d_out (fp32, final)
    gemm_bt<<<dim3(D_ / 128, L_ / 128), 256, 0, stream>>>(
        ob, fwo, fbo, nullptr, nullptr, 0, nullptr, (float*)d_out, D_, 0, 0);
}

// Round 2
// 671.081 us; speedup vs baseline: 1.0853x; 1.0853x over previous
//
#include <hip/hip_runtime.h>
#include <hip/hip_bf16.h>

#define L_ 4096
#define D_ 1024
#define H_ 16
#define HD_ 64
#define NW_ 8
#define WIN_ 512
#define TD (3*D_)

typedef __attribute__((ext_vector_type(8))) short bf16x8;
typedef __attribute__((ext_vector_type(4))) float f32x4;

typedef __attribute__((address_space(1))) const void GVp;
typedef __attribute__((address_space(3))) void LVp;

__device__ __forceinline__ f32x4 mfma16(bf16x8 a, bf16x8 b, f32x4 c) {
    return __builtin_amdgcn_mfma_f32_16x16x32_bf16(a, b, c, 0, 0, 0);
}

__device__ __forceinline__ short f2bfs(float f) {
    __hip_bfloat16 h = __float2bfloat16(f);
    return *reinterpret_cast<short*>(&h);
}

__device__ __forceinline__ float lclamp(float v, float c) {
    return fminf(fmaxf(v, -c), c);
}

// rotary additive term for (seq pos l, feature d), exact fp32
__device__ __forceinline__ float rot_add(const float* rf, int l, int d) {
    const int j = d & 511;
    const float r = rf[j];
    const float inv = exp2f((float)j * 0.02595256324130752f); // 10000^(j/512)
    const float ang = r * (float)l / inv;
    return (d < 512) ? cosf(ang) : sinf(ang);
}

// ---------------------------------------------------------------------------
__global__ __launch_bounds__(256) void rotary_k(
    const float* __restrict__ x,
    const float* __restrict__ rf,
    __hip_bfloat16* __restrict__ x1b)
{
    const int idx = blockIdx.x * 256 + threadIdx.x;   // over L*D
    const int l = idx >> 10;
    const int d = idx & 1023;
    const float v = x[idx] + rot_add(rf, l, d);
    x1b[idx] = __float2bfloat16(lclamp(v, 1.0e4f));
}

// ---------------------------------------------------------------------------
// Weight fp32 -> bf16 converters (same __float2bfloat16 rounding as before,
// so GEMM numerics are bit-identical).
// ---------------------------------------------------------------------------
__global__ __launch_bounds__(256) void wcvt(
    const float* __restrict__ w, __hip_bfloat16* __restrict__ o, unsigned n)
{
    const unsigned i = (blockIdx.x * 256u + threadIdx.x) * 4u;
    if (i < n) {
        float4 v = *(const float4*)&w[i];
        short t[4] = {f2bfs(v.x), f2bfs(v.y), f2bfs(v.z), f2bfs(v.w)};
        *(uint2*)&o[i] = *(uint2*)t;
    }
}

// fused: all four weight tensors in one dispatch (segment boundaries are
// multiples of 4, so a thread's float4 never straddles segments)
__global__ __launch_bounds__(256) void wcvt_all(
    const float* __restrict__ w0, const float* __restrict__ w1,
    const float* __restrict__ w2, const float* __restrict__ w3,
    __hip_bfloat16* __restrict__ o0, __hip_bfloat16* __restrict__ o1,
    __hip_bfloat16* __restrict__ o2, __hip_bfloat16* __restrict__ o3)
{
    const unsigned i = (blockIdx.x * 256u + threadIdx.x) * 4u;
    const float* s; __hip_bfloat16* d; unsigned j;
    if (i < 25165824u)      { s = w0; d = o0; j = i; }
    else if (i < 33554432u) { s = w1; d = o1; j = i - 25165824u; }
    else if (i < 36700160u) { s = w2; d = o2; j = i - 33554432u; }
    else                    { s = w3; d = o3; j = i - 36700160u; }
    float4 v = *(const float4*)&s[j];
    short t[4] = {f2bfs(v.x), f2bfs(v.y), f2bfs(v.z), f2bfs(v.w)};
    *(uint2*)&d[j] = *(uint2*)t;
}

// ---------------------------------------------------------------------------
// FAST GEMM (all-bf16, m97 structure): C[M,N] = A[M,1024] @ Wb[N,1024]^T
// + bias (+ residual). 128x128 tile, BK=32, double-buffered linear LDS,
// global_load_lds(16B) staging for BOTH operands, one __syncthreads per step.
// Accumulation chain identical to gemm_bt (1 MFMA per acc per BK=32 step).
// ---------------------------------------------------------------------------
__global__ __launch_bounds__(256) void gemm_fb(
    const __hip_bfloat16* __restrict__ A,
    const __hip_bfloat16* __restrict__ Wb,
    const float* __restrict__ bias,
    const float* __restrict__ xin,
    const float* __restrict__ rf,
    int residMode,
    __hip_bfloat16* __restrict__ Cb,
    float* __restrict__ Cf,
    int N, int wStrideW, int wStrideB)
{
    // XCD-aware bijective swizzle (n-major chunks per XCD)
    int bn = blockIdx.x, bm = blockIdx.y;
    {
        const int gx = gridDim.x, gy = gridDim.y;
        const int nblk = gx * gy;
        if ((nblk & 7) == 0) {
            const int lid = blockIdx.y * gx + blockIdx.x;
            const int per = nblk >> 3;
            const int t = (lid & 7) * per + (lid >> 3);
            bn = t / gy;
            bm = t - bn * gy;
        }
    }
    const int m0 = bm * 128;
    const int n0 = bn * 128;
    const int win = m0 / WIN_;
    const __hip_bfloat16* Wp = Wb + (size_t)win * (size_t)wStrideW;
    const float* Bp = bias + (size_t)win * (size_t)wStrideB;

    __shared__ __align__(16) short As[2][128 * 32];
    __shared__ __align__(16) short Bs[2][128 * 32];

    const int tid  = threadIdx.x;
    const int lane = tid & 63;
    const int wave = tid >> 6;
    const int wm = (wave & 1) * 64;
    const int wn = (wave >> 1) * 64;
    const int lrow = lane & 15;
    const int kg   = lane >> 4;

    // staging: thread tid covers rows (tid>>2) and (tid>>2)+64, k-part tid&3.
    // LDS dest byte = tid*16  ->  layout [row][32] shorts (linear, gload_lds).
    const int row0 = tid >> 2;
    const int part = tid & 3;
    const short* Ag  = (const short*)A  + (size_t)(m0 + row0) * D_ + part * 8;
    const short* Ag2 = Ag + (size_t)64 * D_;
    const short* Wg  = (const short*)Wp + (size_t)(n0 + row0) * D_ + part * 8;
    const short* Wg2 = Wg + (size_t)64 * D_;

    auto stage = [&](int k0, int buf) {
        __builtin_amdgcn_global_load_lds((GVp*)(Ag  + k0), (LVp*)&As[buf][wave * 512],        16, 0, 0);
        __builtin_amdgcn_global_load_lds((GVp*)(Ag2 + k0), (LVp*)&As[buf][2048 + wave * 512], 16, 0, 0);
        __builtin_amdgcn_global_load_lds((GVp*)(Wg  + k0), (LVp*)&Bs[buf][wave * 512],        16, 0, 0);
        __builtin_amdgcn_global_load_lds((GVp*)(Wg2 + k0), (LVp*)&Bs[buf][2048 + wave * 512], 16, 0, 0);
    };

    const f32x4 zero4 = {0.f, 0.f, 0.f, 0.f};
    f32x4 acc[4][4];
    #pragma unroll
    for (int i = 0; i < 4; i++)
        #pragma unroll
        for (int jj = 0; jj < 4; jj++) acc[i][jj] = zero4;

    stage(0, 0);
    const int nsteps = D_ / 32;           // 32
    for (int i = 0; i < nsteps; i++) {
        const int cur = i & 1;
        __syncthreads();                  // drains vmcnt: buf[cur] staged; prev reads done
        if (i + 1 < nsteps) stage((i + 1) * 32, 1 - cur);
        bf16x8 af[4], bfr[4];
        #pragma unroll
        for (int ii = 0; ii < 4; ii++)
            af[ii] = *(const bf16x8*)&As[cur][(wm + ii * 16 + lrow) * 32 + kg * 8];
        #pragma unroll
        for (int jj = 0; jj < 4; jj++)
            bfr[jj] = *(const bf16x8*)&Bs[cur][(wn + jj * 16 + lrow) * 32 + kg * 8];
        #pragma unroll
        for (int ii = 0; ii < 4; ii++)
            #pragma unroll
            for (int jj = 0; jj < 4; jj++)
                acc[ii][jj] = mfma16(af[ii], bfr[jj], acc[ii][jj]);
    }

    // C/D layout: row = kg*4 + r, col = lrow  (within each 16x16 tile)
    #pragma unroll
    for (int jj = 0; jj < 4; jj++) {
        const int col = n0 + wn + jj * 16 + lrow;
        const float bv = Bp[col];
        #pragma unroll
        for (int i = 0; i < 4; i++) {
            #pragma unroll
            for (int r = 0; r < 4; r++) {
                const int row = m0 + wm + i * 16 + kg * 4 + r;
                float v = acc[i][jj][r] + bv;
                if (residMode) {
                    v += xin[(size_t)row * D_ + col] + rot_add(rf, row, col);
                }
                v = lclamp(v, 1.0e4f);
                if (Cf) Cf[(size_t)row * N + col] = v;
                else    Cb[(size_t)row * N + col] = __float2bfloat16(v);
            }
        }
    }
}

// ---------------------------------------------------------------------------
// FALLBACK GEMM (fp32 W, reg-staged) — used when ws_size can't hold bf16
// weights. Unchanged from round 1.
// ---------------------------------------------------------------------------
__global__ __launch_bounds__(256) void gemm_bt(
    const __hip_bfloat16* __restrict__ A,
    const float* __restrict__ Wt,
    const float* __restrict__ bias,
    const float* __restrict__ xin,
    const float* __restrict__ rf,
    int residMode,
    __hip_bfloat16* __restrict__ Cb,
    float* __restrict__ Cf,
    int N, int wStrideW, int wStrideB)
{
    const int K = D_;
    int bn = blockIdx.x, bm = blockIdx.y;
    {
        const int gx = gridDim.x, gy = gridDim.y;
        const int nblk = gx * gy;
        if ((nblk & 7) == 0) {
            const int lid = blockIdx.y * gx + blockIdx.x;
            const int per = nblk >> 3;
            const int t = (lid & 7) * per + (lid >> 3);
            bn = t / gy;
            bm = t - bn * gy;
        }
    }
    const int m0 = bm * 128;
    const int n0 = bn * 128;
    const int win = m0 / WIN_;
    const float* Wp = Wt + (size_t)win * (size_t)wStrideW;
    const float* Bp = bias + (size_t)win * (size_t)wStrideB;

    __shared__ __align__(16) short As[2][128 * 40];
    __shared__ __align__(16) short Bs[2][128 * 40];

    const int tid  = threadIdx.x;
    const int lane = tid & 63;
    const int wave = tid >> 6;
    const int wm = (wave & 1) * 64;
    const int wn = (wave >> 1) * 64;
    const int lrow = lane & 15;
    const int kg   = lane >> 4;

    const int row0 = tid >> 2;
    const int part = tid & 3;
    const size_t aoff0 = (size_t)(m0 + row0) * K + part * 8;
    const size_t aoff1 = (size_t)(m0 + row0 + 64) * K + part * 8;
    const size_t woff0 = (size_t)(n0 + row0) * K + part * 8;
    const size_t woff1 = (size_t)(n0 + row0 + 64) * K + part * 8;

    uint4 ar[2];
    float4 wr[4];
    auto loadRegs = [&](int k0) {
        ar[0] = *(const uint4*)&A[aoff0 + k0];
        ar[1] = *(const uint4*)&A[aoff1 + k0];
        wr[0] = *(const float4*)&Wp[woff0 + k0];
        wr[1] = *(const float4*)&Wp[woff0 + k0 + 4];
        wr[2] = *(const float4*)&Wp[woff1 + k0];
        wr[3] = *(const float4*)&Wp[woff1 + k0 + 4];
    };
    auto writeLDS = [&](int b) {
        *(uint4*)&As[b][row0 * 40 + part * 8] = ar[0];
        *(uint4*)&As[b][(row0 + 64) * 40 + part * 8] = ar[1];
        short t0[8], t1[8];
        t0[0]=f2bfs(wr[0].x); t0[1]=f2bfs(wr[0].y); t0[2]=f2bfs(wr[0].z); t0[3]=f2bfs(wr[0].w);
        t0[4]=f2bfs(wr[1].x); t0[5]=f2bfs(wr[1].y); t0[6]=f2bfs(wr[1].z); t0[7]=f2bfs(wr[1].w);
        t1[0]=f2bfs(wr[2].x); t1[1]=f2bfs(wr[2].y); t1[2]=f2bfs(wr[2].z); t1[3]=f2bfs(wr[2].w);
        t1[4]=f2bfs(wr[3].x); t1[5]=f2bfs(wr[3].y); t1[6]=f2bfs(wr[3].z); t1[7]=f2bfs(wr[3].w);
        *(uint4*)&Bs[b][row0 * 40 + part * 8] = *(uint4*)t0;
        *(uint4*)&Bs[b][(row0 + 64) * 40 + part * 8] = *(uint4*)t1;
    };

    const f32x4 zero4 = {0.f, 0.f, 0.f, 0.f};
    f32x4 acc[4][4];
    #pragma unroll
    for (int i = 0; i < 4; i++)
        #pragma unroll
        for (int jj = 0; jj < 4; jj++) acc[i][jj] = zero4;

    const int nsteps = K / 32;
    loadRegs(0);
    writeLDS(0);
    loadRegs(32);

    for (int i = 0; i < nsteps; i++) {
        asm volatile("s_waitcnt lgkmcnt(0)" ::: "memory");
        __builtin_amdgcn_s_barrier();
        const int cur = i & 1;
        bf16x8 af[4], bfr[4];
        #pragma unroll
        for (int ii = 0; ii < 4; ii++)
            af[ii] = *(const bf16x8*)&As[cur][(wm + ii * 16 + lrow) * 40 + kg * 8];
        #pragma unroll
        for (int jj = 0; jj < 4; jj++)
            bfr[jj] = *(const bf16x8*)&Bs[cur][(wn + jj * 16 + lrow) * 40 + kg * 8];
        #pragma unroll
        for (int ii = 0; ii < 4; ii++)
            #pragma unroll
            for (int jj = 0; jj < 4; jj++)
                acc[ii][jj] = mfma16(af[ii], bfr[jj], acc[ii][jj]);
        if (i + 1 < nsteps) {
            writeLDS(1 - cur);
            if (i + 2 < nsteps) loadRegs((i + 2) * 32);
        }
    }

    #pragma unroll
    for (int jj = 0; jj < 4; jj++) {
        const int col = n0 + wn + jj * 16 + lrow;
        const float bv = Bp[col];
        #pragma unroll
        for (int i = 0; i < 4; i++) {
            #pragma unroll
            for (int r = 0; r < 4; r++) {
                const int row = m0 + wm + i * 16 + kg * 4 + r;
                float v = acc[i][jj][r] + bv;
                if (residMode) {
                    v += xin[(size_t)row * D_ + col] + rot_add(rf, row, col);
                }
                v = lclamp(v, 1.0e4f);
                if (Cf) Cf[(size_t)row * N + col] = v;
                else    Cb[(size_t)row * N + col] = __float2bfloat16(v);
            }
        }
    }
}

// ---------------------------------------------------------------------------
// Transpose V out of qkv: Vt[h][vd][l] = qkv[l][2*D + h*64 + vd]
// ---------------------------------------------------------------------------
__global__ __launch_bounds__(256) void transpose_v(
    const __hip_bfloat16* __restrict__ qkv,
    __hip_bfloat16* __restrict__ Vt)
{
    __shared__ __align__(16) short Ts[64 * 72];
    const int t = threadIdx.x;
    const int l0 = blockIdx.x * 64;
    const int h = blockIdx.y;
    #pragma unroll
    for (int p = 0; p < 2; p++) {
        const int idx = p * 256 + t;
        const int key = idx >> 3, part = idx & 7;
        *(uint4*)&Ts[key * 72 + part * 8] =
            *(const uint4*)&qkv[(size_t)(l0 + key) * TD + 2 * D_ + h * HD_ + part * 8];
    }
    __syncthreads();
    #pragma unroll
    for (int p = 0; p < 2; p++) {
        const int idx = p * 256 + t;
        const int vd = idx >> 3, part = idx & 7;
        short tmp[8];
        #pragma unroll
        for (int j = 0; j < 8; j++) tmp[j] = Ts[(part * 8 + j) * 72 + vd];
        *(uint4*)&Vt[(size_t)(h * HD_ + vd) * L_ + l0 + part * 8] = *(uint4*)tmp;
    }
}

// ---------------------------------------------------------------------------
// Flash attention v4 + T5 setprio around MFMA clusters.
// ---------------------------------------------------------------------------
__global__ __launch_bounds__(256, 3) void attn_k(
    const __hip_bfloat16* __restrict__ qkv,
    const __hip_bfloat16* __restrict__ Vt,
    __hip_bfloat16* __restrict__ o,
    int Sw)
{
    const int tid  = threadIdx.x;
    const int lane = tid & 63;
    const int wave = tid >> 6;
    const int lrow = lane & 15;
    const int kg   = lane >> 4;

    int bx = blockIdx.x, by = blockIdx.y, bz = blockIdx.z;
    {
        const int gx = gridDim.x, gy = gridDim.y, gz = gridDim.z;
        const int nblk = gx * gy * gz;
        if ((nblk & 7) == 0) {
            const int lid = (blockIdx.z * gy + blockIdx.y) * gx + blockIdx.x;
            const int per = nblk >> 3;
            const int t = (lid & 7) * per + (lid >> 3);
            bx = t % gx;
            const int rest = t / gx;
            by = rest % gy;
            bz = rest / gy;
        }
    }
    const int h = by;
    const int wbase = bz * Sw;
    const int q0 = wbase + bx * 64 + wave * 16;

    const short* Kglb = reinterpret_cast<const short*>(qkv)
                        + (size_t)wbase * TD + D_ + h * HD_;
    const short* Vtglb = reinterpret_cast<const short*>(Vt)
                         + (size_t)h * HD_ * L_ + wbase;
    const __hip_bfloat16* Q = qkv + (size_t)q0 * TD + h * HD_;

    __shared__ __align__(16) short Ks[2][64 * 64];
    __shared__ __align__(16) short Vs[2][64 * 64];
    __shared__ __align__(16) short Ps[4][16 * 72];
    short* myP = &Ps[wave][0];

    const bf16x8 qf0 = *(const bf16x8*)&Q[(size_t)lrow * TD + kg * 8];
    const bf16x8 qf1 = *(const bf16x8*)&Q[(size_t)lrow * TD + 32 + kg * 8];

    const f32x4 zero4 = {0.f, 0.f, 0.f, 0.f};
    float lacc[4];
    f32x4 oacc[4];
    #pragma unroll
    for (int r = 0; r < 4; r++) lacc[r] = 0.f;
    #pragma unroll
    for (int t = 0; t < 4; t++) oacc[t] = zero4;

    auto stage = [&](int c, int buf) {
        const int s0 = (wave & 1) * 256;
        if (wave < 2) {
            #pragma unroll
            for (int j = 0; j < 4; j++) {
                const int s = s0 + j * 64 + lane;
                const int r = s >> 3;
                const int cb = (s & 7) ^ (r & 7);
                const short* src = Kglb + (size_t)(c + r) * TD + cb * 8;
                __builtin_amdgcn_global_load_lds(
                    (GVp*)src, (LVp*)&Ks[buf][(s0 + j * 64) * 8], 16, 0, 0);
            }
        } else {
            #pragma unroll
            for (int j = 0; j < 4; j++) {
                const int s = s0 + j * 64 + lane;
                const int r = s >> 3;
                const int cb = (s & 7) ^ (r & 7);
                const short* src = Vtglb + (size_t)r * L_ + c + cb * 8;
                __builtin_amdgcn_global_load_lds(
                    (GVp*)src, (LVp*)&Vs[buf][(s0 + j * 64) * 8], 16, 0, 0);
            }
        }
    };

    const int ntiles = Sw >> 6;
    stage(0, 0);

    // p = exp2(fma(s, 0.125*log2e, -16*log2e))
    const float SC = 0.18033688011112042f;
    const float MB = -23.083120654223414f;

    for (int i = 0; i < ntiles; i++) {
        const int cur = i & 1;
        __syncthreads();
        if (i + 1 < ntiles) stage((i + 1) << 6, 1 - cur);

        const short* Kl = Ks[cur];
        const short* Vl = Vs[cur];
        const int sw = lrow & 7;

        f32x4 s[4];
        __builtin_amdgcn_s_setprio(1);
        #pragma unroll
        for (int kt = 0; kt < 4; kt++) {
            const int key = kt * 16 + lrow;
            bf16x8 k0 = *(const bf16x8*)&Kl[key * 64 + ((kg     ^ sw) * 8)];
            bf16x8 k1 = *(const bf16x8*)&Kl[key * 64 + (((kg+4) ^ sw) * 8)];
            f32x4 acc = zero4;
            acc = mfma16(qf0, k0, acc);
            acc = mfma16(qf1, k1, acc);
            s[kt] = acc;
        }
        __builtin_amdgcn_s_setprio(0);

        asm volatile("" ::: "memory");
        #pragma unroll
        for (int kt = 0; kt < 4; kt++) {
            #pragma unroll
            for (int r = 0; r < 4; r++) {
                const float p = exp2f(fmaf(s[kt][r], SC, MB));
                lacc[r] += p;
                myP[(kg * 4 + r) * 72 + kt * 16 + lrow] = f2bfs(p);
            }
        }
        asm volatile("s_waitcnt lgkmcnt(0)" ::: "memory");
        const bf16x8 pf0 = *(const bf16x8*)&myP[lrow * 72 + kg * 8];
        const bf16x8 pf1 = *(const bf16x8*)&myP[lrow * 72 + 32 + kg * 8];

        __builtin_amdgcn_s_setprio(1);
        #pragma unroll
        for (int t = 0; t < 4; t++) {
            const int vd = t * 16 + lrow;
            bf16x8 v0 = *(const bf16x8*)&Vl[vd * 64 + ((kg     ^ sw) * 8)];
            bf16x8 v1 = *(const bf16x8*)&Vl[vd * 64 + (((kg+4) ^ sw) * 8)];
            oacc[t] = mfma16(pf0, v0, oacc[t]);
            oacc[t] = mfma16(pf1, v1, oacc[t]);
        }
        __builtin_amdgcn_s_setprio(0);
    }

    #pragma unroll
    for (int off = 1; off < 16; off <<= 1)
        #pragma unroll
        for (int r = 0; r < 4; r++)
            lacc[r] += __shfl_xor(lacc[r], off, 64);

    #pragma unroll
    for (int t = 0; t < 4; t++) {
        #pragma unroll
        for (int r = 0; r < 4; r++) {
            const int row = q0 + kg * 4 + r;
            const int col = h * HD_ + t * 16 + lrow;
            o[(size_t)row * D_ + col] =
                __float2bfloat16(lclamp(oacc[t][r] / lacc[r], 1.0e4f));
        }
    }
}

// ---------------------------------------------------------------------------
extern "C" void kernel_launch(void* const* d_in, const int* in_sizes, int n_in,
                              void* d_out, int out_size, void* d_ws, size_t ws_size,
                              hipStream_t stream)
{
    const float* x   = (const float*)d_in[0];
    const float* rf  = (const float*)d_in[1];
    const float* wwi = (const float*)d_in[2];
    const float* wbi = (const float*)d_in[3];
    const float* wwo = (const float*)d_in[4];
    const float* wbo = (const float*)d_in[5];
    const float* fwi = (const float*)d_in[6];
    const float* fbi = (const float*)d_in[7];
    const float* fwo = (const float*)d_in[8];
    const float* fbo = (const float*)d_in[9];

    char* ws = (char*)d_ws;
    __hip_bfloat16* qkv = (__hip_bfloat16*)(ws);                 // [L,3D] 24 MiB
    __hip_bfloat16* ob  = (__hip_bfloat16*)(ws + (24u << 20));   // [L,D]   8 MiB
    __hip_bfloat16* xsc = (__hip_bfloat16*)d_out;                // [L,D] bf16 scratch
    __hip_bfloat16* Vt  = (__hip_bfloat16*)d_out;                // [H,HD,L] bf16

    const size_t MB1 = 1u << 20;
    // mode 2: all bf16 weights resident (72 MiB @ ws+32M); mode 1: shared
    // 48 MiB buffer, JIT convert before each gemm; mode 0: fp32 fallback.
    const int mode = (ws_size >= 104 * MB1) ? 2 : (ws_size >= 80 * MB1 ? 1 : 0);

    __hip_bfloat16* wwib = (__hip_bfloat16*)(ws + 32 * MB1);
    __hip_bfloat16* wwob = wwib;
    __hip_bfloat16* fwib = wwib;
    __hip_bfloat16* fwob = wwib;
    if (mode == 2) {
        wwob = (__hip_bfloat16*)(ws + 80 * MB1);
        fwib = (__hip_bfloat16*)(ws + 96 * MB1);
        fwob = (__hip_bfloat16*)(ws + 102 * MB1);
        wcvt_all<<<dim3(36864), 256, 0, stream>>>(
            wwi, wwo, fwi, fwo, wwib, wwob, fwib, fwob);
    } else if (mode == 1) {
        wcvt<<<dim3(24576), 256, 0, stream>>>(wwi, wwib, 25165824u);
    }

    // 1. rotary add -> x1 (bf16)
    rotary_k<<<dim3(L_ * D_ / 256), 256, 0, stream>>>(x, rf, xsc);

    // 2. per-window qkv = x1 @ win_w_in^T + win_b_in
    if (mode) gemm_fb<<<dim3(TD / 128, L_ / 128), 256, 0, stream>>>(
        xsc, wwib, wbi, nullptr, nullptr, 0, qkv, nullptr, TD, TD * D_, TD);
    else gemm_bt<<<dim3(TD / 128, L_ / 128), 256, 0, stream>>>(
        xsc, wwi, wbi, nullptr, nullptr, 0, qkv, nullptr, TD, TD * D_, TD);

    // 2b. V transpose
    transpose_v<<<dim3(L_ / 64, H_), 256, 0, stream>>>(qkv, Vt);

    // 3. windowed attention (Sw = 512)
    attn_k<<<dim3(WIN_ / 64, H_, NW_), 256, 0, stream>>>(qkv, Vt, ob, WIN_);

    // 4. x2 = (x + rotary, exact fp32) + o @ win_w_out^T + win_b_out
    if (mode == 1) wcvt<<<dim3(8192), 256, 0, stream>>>(wwo, wwob, 8388608u);
    if (mode) gemm_fb<<<dim3(D_ / 128, L_ / 128), 256, 0, stream>>>(
        ob, wwob, wbo, x, rf, 1, xsc, nullptr, D_, D_ * D_, D_);
    else gemm_bt<<<dim3(D_ / 128, L_ / 128), 256, 0, stream>>>(
        ob, wwo, wbo, x, rf, 1, xsc, nullptr, D_, D_ * D_, D_);

    // 5. final qkv = x2 @ fin_w_in^T + fin_b_in
    if (mode == 1) wcvt<<<dim3(3072), 256, 0, stream>>>(fwi, fwib, 3145728u);
    if (mode) gemm_fb<<<dim3(TD / 128, L_ / 128), 256, 0, stream>>>(
        xsc, fwib, fbi, nullptr, nullptr, 0, qkv, nullptr, TD, 0, 0);
    else gemm_bt<<<dim3(TD / 128, L_ / 128), 256, 0, stream>>>(
        xsc, fwi, fbi, nullptr, nullptr, 0, qkv, nullptr, TD, 0, 0);

    // 5b. V transpose
    transpose_v<<<dim3(L_ / 64, H_), 256, 0, stream>>>(qkv, Vt);

    // 6. global attention (Sw = 4096)
    attn_k<<<dim3(L_ / 64, H_, 1), 256, 0, stream>>>(qkv, Vt, ob, L_);

    // 7. out = o @ fin_w_out^T + fin_b_out  -> d_out (fp32, final)
    if (mode == 1) wcvt<<<dim3(1024), 256, 0, stream>>>(fwo, fwob, 1048576u);
    if (mode) gemm_fb<<<dim3(D_ / 128, L_ / 128), 256, 0, stream>>>(
        ob, fwob, fbo, nullptr, nullptr, 0, nullptr, (float*)d_out, D_, 0, 0);
    else gemm_bt<<<dim3(D_ / 128, L_ / 128), 256, 0, stream>>>(
        ob, fwo, fbo, nullptr, nullptr, 0, nullptr, (float*)d_out, D_, 0, 0);
}

// Round 3
// 669.512 us; speedup vs baseline: 1.0878x; 1.0023x over previous
//
#include <hip/hip_runtime.h>
#include <hip/hip_bf16.h>

#define L_ 4096
#define D_ 1024
#define H_ 16
#define HD_ 64
#define NW_ 8
#define WIN_ 512
#define TD (3*D_)

typedef __attribute__((ext_vector_type(8))) short bf16x8;
typedef __attribute__((ext_vector_type(4))) float f32x4;

typedef __attribute__((address_space(1))) const void GVp;
typedef __attribute__((address_space(3))) void LVp;

__device__ __forceinline__ f32x4 mfma16(bf16x8 a, bf16x8 b, f32x4 c) {
    return __builtin_amdgcn_mfma_f32_16x16x32_bf16(a, b, c, 0, 0, 0);
}

__device__ __forceinline__ short f2bfs(float f) {
    __hip_bfloat16 h = __float2bfloat16(f);
    return *reinterpret_cast<short*>(&h);
}

__device__ __forceinline__ float lclamp(float v, float c) {
    return fminf(fmaxf(v, -c), c);
}

// rotary additive term for (seq pos l, feature d), exact fp32
__device__ __forceinline__ float rot_add(const float* rf, int l, int d) {
    const int j = d & 511;
    const float r = rf[j];
    const float inv = exp2f((float)j * 0.02595256324130752f); // 10000^(j/512)
    const float ang = r * (float)l / inv;
    return (d < 512) ? cosf(ang) : sinf(ang);
}

// ---------------------------------------------------------------------------
__global__ __launch_bounds__(256) void rotary_k(
    const float* __restrict__ x,
    const float* __restrict__ rf,
    __hip_bfloat16* __restrict__ x1b)
{
    const int idx = blockIdx.x * 256 + threadIdx.x;   // over L*D
    const int l = idx >> 10;
    const int d = idx & 1023;
    const float v = x[idx] + rot_add(rf, l, d);
    x1b[idx] = __float2bfloat16(lclamp(v, 1.0e4f));
}

// ---------------------------------------------------------------------------
// fused fp32->bf16 weight convert (mode: big workspace only)
// ---------------------------------------------------------------------------
__global__ __launch_bounds__(256) void wcvt_all(
    const float* __restrict__ w0, const float* __restrict__ w1,
    const float* __restrict__ w2, const float* __restrict__ w3,
    __hip_bfloat16* __restrict__ o0, __hip_bfloat16* __restrict__ o1,
    __hip_bfloat16* __restrict__ o2, __hip_bfloat16* __restrict__ o3)
{
    const unsigned i = (blockIdx.x * 256u + threadIdx.x) * 4u;
    const float* s; __hip_bfloat16* d; unsigned j;
    if (i < 25165824u)      { s = w0; d = o0; j = i; }
    else if (i < 33554432u) { s = w1; d = o1; j = i - 25165824u; }
    else if (i < 36700160u) { s = w2; d = o2; j = i - 33554432u; }
    else                    { s = w3; d = o3; j = i - 36700160u; }
    float4 v = *(const float4*)&s[j];
    short t[4] = {f2bfs(v.x), f2bfs(v.y), f2bfs(v.z), f2bfs(v.w)};
    *(uint2*)&d[j] = *(uint2*)t;
}

// ---------------------------------------------------------------------------
// Unified GEMM: C[M,N] = A[M,1024](bf16) @ W[N,1024]^T + bias (+residual).
// WF32=1: W read as fp32 from global, staged fp32 into LDS via
// global_load_lds, converted to bf16 at frag-read (bit-identical numerics,
// zero extra global memory). WF32=0: W already bf16.
// m97 structure: 128x128 tile, BK=32, double-buffered LDS, one
// __syncthreads per step; async staging for BOTH operands.
// LDS XOR swizzle (rule #21: pre-swizzled global SOURCE + swizzled READ,
// linear LDS dest):
//   bf16 tile  [128 rows][4 x 16B grp]: grp' = grp ^ ((row>>1)&3)  -> 2-way
//   fp32 tile  [128 rows][8 x 16B grp]: grp' = grp ^ (row&7)       -> 2-way
// ---------------------------------------------------------------------------
template<int WF32>
__global__ __launch_bounds__(256) void gemm_u(
    const __hip_bfloat16* __restrict__ A,
    const void* __restrict__ Wv,
    const float* __restrict__ bias,
    const float* __restrict__ xin,
    const float* __restrict__ rf,
    int residMode,
    __hip_bfloat16* __restrict__ Cb,
    float* __restrict__ Cf,
    int N, int wStrideW, int wStrideB)
{
    // XCD-aware bijective swizzle (n-major chunks per XCD)
    int bn = blockIdx.x, bm = blockIdx.y;
    {
        const int gx = gridDim.x, gy = gridDim.y;
        const int nblk = gx * gy;
        if ((nblk & 7) == 0) {
            const int lid = blockIdx.y * gx + blockIdx.x;
            const int per = nblk >> 3;
            const int t = (lid & 7) * per + (lid >> 3);
            bn = t / gy;
            bm = t - bn * gy;
        }
    }
    const int m0 = bm * 128;
    const int n0 = bn * 128;
    const int win = m0 / WIN_;

    const short* Wb = (const short*)Wv + (WF32 ? 0 : (size_t)win * (size_t)wStrideW);
    const float* Wf = (const float*)Wv + (WF32 ? (size_t)win * (size_t)wStrideW : 0);
    const float* Bp = bias + (size_t)win * (size_t)wStrideB;

    __shared__ __align__(16) short As[2][128 * 32];              // bf16 A tile
    __shared__ __align__(16) short Bs[2][WF32 ? 128 * 64 : 128 * 32];

    const int tid  = threadIdx.x;
    const int lane = tid & 63;
    const int wave = tid >> 6;
    const int wm = (wave & 1) * 64;
    const int wn = (wave >> 1) * 64;
    const int lrow = lane & 15;
    const int kg   = lane >> 4;

    // ---- A staging: 512 slots of 16B; thread covers slots tid, tid+256.
    const int sA0 = tid,        rA0 = sA0 >> 2, gA0 = (sA0 & 3) ^ ((rA0 >> 1) & 3);
    const int sA1 = tid + 256,  rA1 = sA1 >> 2, gA1 = (sA1 & 3) ^ ((rA1 >> 1) & 3);
    const short* Asrc0 = (const short*)A + (size_t)(m0 + rA0) * D_ + gA0 * 8;
    const short* Asrc1 = (const short*)A + (size_t)(m0 + rA1) * D_ + gA1 * 8;

    // ---- W staging (bf16 path): same slot scheme as A.
    const short* Wsrc0 = Wb + (size_t)(n0 + rA0) * D_ + gA0 * 8;
    const short* Wsrc1 = Wb + (size_t)(n0 + rA1) * D_ + gA1 * 8;

    // ---- W staging (fp32 path): 1024 slots of 16B (4 floats); thread
    // covers slots tid+256*j, j=0..3.
    const float* Fsrc[4];
    if (WF32) {
        #pragma unroll
        for (int j = 0; j < 4; j++) {
            const int s = tid + 256 * j;
            const int row = s >> 3;
            const int g8 = (s & 7) ^ (row & 7);
            Fsrc[j] = Wf + (size_t)(n0 + row) * D_ + g8 * 4;
        }
    }

    auto stage = [&](int k0, int buf) {
        __builtin_amdgcn_global_load_lds((GVp*)(Asrc0 + k0), (LVp*)&As[buf][wave * 512],        16, 0, 0);
        __builtin_amdgcn_global_load_lds((GVp*)(Asrc1 + k0), (LVp*)&As[buf][2048 + wave * 512], 16, 0, 0);
        if (WF32) {
            #pragma unroll
            for (int j = 0; j < 4; j++)
                __builtin_amdgcn_global_load_lds((GVp*)(Fsrc[j] + k0), (LVp*)&Bs[buf][j * 2048 + wave * 512], 16, 0, 0);
        } else {
            __builtin_amdgcn_global_load_lds((GVp*)(Wsrc0 + k0), (LVp*)&Bs[buf][wave * 512],        16, 0, 0);
            __builtin_amdgcn_global_load_lds((GVp*)(Wsrc1 + k0), (LVp*)&Bs[buf][2048 + wave * 512], 16, 0, 0);
        }
    };

    const f32x4 zero4 = {0.f, 0.f, 0.f, 0.f};
    f32x4 acc[4][4];
    #pragma unroll
    for (int i = 0; i < 4; i++)
        #pragma unroll
        for (int jj = 0; jj < 4; jj++) acc[i][jj] = zero4;

    stage(0, 0);
    const int nsteps = D_ / 32;           // 32
    for (int i = 0; i < nsteps; i++) {
        const int cur = i & 1;
        __syncthreads();                  // drains vmcnt: buf[cur] staged; prev reads done
        if (i + 1 < nsteps) stage((i + 1) * 32, 1 - cur);

        bf16x8 af[4], bfr[4];
        #pragma unroll
        for (int ii = 0; ii < 4; ii++) {
            const int ar_ = wm + ii * 16 + lrow;
            af[ii] = *(const bf16x8*)&As[cur][ar_ * 32 + ((kg ^ ((ar_ >> 1) & 3)) * 8)];
        }
        #pragma unroll
        for (int jj = 0; jj < 4; jj++) {
            const int wr_ = wn + jj * 16 + lrow;
            if (WF32) {
                // fp32 tile: row stride 32 floats = 64 shorts; two 16B groups
                const float4 wlo = *(const float4*)&Bs[cur][wr_ * 64 + (((2 * kg)     ^ (wr_ & 7)) * 8)];
                const float4 whi = *(const float4*)&Bs[cur][wr_ * 64 + (((2 * kg + 1) ^ (wr_ & 7)) * 8)];
                short t[8] = {f2bfs(wlo.x), f2bfs(wlo.y), f2bfs(wlo.z), f2bfs(wlo.w),
                              f2bfs(whi.x), f2bfs(whi.y), f2bfs(whi.z), f2bfs(whi.w)};
                bfr[jj] = *(const bf16x8*)t;
            } else {
                bfr[jj] = *(const bf16x8*)&Bs[cur][wr_ * 32 + ((kg ^ ((wr_ >> 1) & 3)) * 8)];
            }
        }
        #pragma unroll
        for (int ii = 0; ii < 4; ii++)
            #pragma unroll
            for (int jj = 0; jj < 4; jj++)
                acc[ii][jj] = mfma16(af[ii], bfr[jj], acc[ii][jj]);
    }

    // C/D layout: row = kg*4 + r, col = lrow  (within each 16x16 tile)
    #pragma unroll
    for (int jj = 0; jj < 4; jj++) {
        const int col = n0 + wn + jj * 16 + lrow;
        const float bv = Bp[col];
        #pragma unroll
        for (int i = 0; i < 4; i++) {
            #pragma unroll
            for (int r = 0; r < 4; r++) {
                const int row = m0 + wm + i * 16 + kg * 4 + r;
                float v = acc[i][jj][r] + bv;
                if (residMode) {
                    v += xin[(size_t)row * D_ + col] + rot_add(rf, row, col);
                }
                v = lclamp(v, 1.0e4f);
                if (Cf) Cf[(size_t)row * N + col] = v;
                else    Cb[(size_t)row * N + col] = __float2bfloat16(v);
            }
        }
    }
}

// ---------------------------------------------------------------------------
// Transpose V out of qkv: Vt[h][vd][l] = qkv[l][2*D + h*64 + vd]
// ---------------------------------------------------------------------------
__global__ __launch_bounds__(256) void transpose_v(
    const __hip_bfloat16* __restrict__ qkv,
    __hip_bfloat16* __restrict__ Vt)
{
    __shared__ __align__(16) short Ts[64 * 72];
    const int t = threadIdx.x;
    const int l0 = blockIdx.x * 64;
    const int h = blockIdx.y;
    #pragma unroll
    for (int p = 0; p < 2; p++) {
        const int idx = p * 256 + t;
        const int key = idx >> 3, part = idx & 7;
        *(uint4*)&Ts[key * 72 + part * 8] =
            *(const uint4*)&qkv[(size_t)(l0 + key) * TD + 2 * D_ + h * HD_ + part * 8];
    }
    __syncthreads();
    #pragma unroll
    for (int p = 0; p < 2; p++) {
        const int idx = p * 256 + t;
        const int vd = idx >> 3, part = idx & 7;
        short tmp[8];
        #pragma unroll
        for (int j = 0; j < 8; j++) tmp[j] = Ts[(part * 8 + j) * 72 + vd];
        *(uint4*)&Vt[(size_t)(h * HD_ + vd) * L_ + l0 + part * 8] = *(uint4*)tmp;
    }
}

// ---------------------------------------------------------------------------
// Flash attention v4 (fixed-max streaming softmax), XCD block swizzle.
// (setprio reverted: measured -5% in round 2.)
// ---------------------------------------------------------------------------
__global__ __launch_bounds__(256, 3) void attn_k(
    const __hip_bfloat16* __restrict__ qkv,
    const __hip_bfloat16* __restrict__ Vt,
    __hip_bfloat16* __restrict__ o,
    int Sw)
{
    const int tid  = threadIdx.x;
    const int lane = tid & 63;
    const int wave = tid >> 6;
    const int lrow = lane & 15;
    const int kg   = lane >> 4;

    int bx = blockIdx.x, by = blockIdx.y, bz = blockIdx.z;
    {
        const int gx = gridDim.x, gy = gridDim.y, gz = gridDim.z;
        const int nblk = gx * gy * gz;
        if ((nblk & 7) == 0) {
            const int lid = (blockIdx.z * gy + blockIdx.y) * gx + blockIdx.x;
            const int per = nblk >> 3;
            const int t = (lid & 7) * per + (lid >> 3);
            bx = t % gx;
            const int rest = t / gx;
            by = rest % gy;
            bz = rest / gy;
        }
    }
    const int h = by;
    const int wbase = bz * Sw;
    const int q0 = wbase + bx * 64 + wave * 16;

    const short* Kglb = reinterpret_cast<const short*>(qkv)
                        + (size_t)wbase * TD + D_ + h * HD_;
    const short* Vtglb = reinterpret_cast<const short*>(Vt)
                         + (size_t)h * HD_ * L_ + wbase;
    const __hip_bfloat16* Q = qkv + (size_t)q0 * TD + h * HD_;

    __shared__ __align__(16) short Ks[2][64 * 64];
    __shared__ __align__(16) short Vs[2][64 * 64];
    __shared__ __align__(16) short Ps[4][16 * 72];
    short* myP = &Ps[wave][0];

    const bf16x8 qf0 = *(const bf16x8*)&Q[(size_t)lrow * TD + kg * 8];
    const bf16x8 qf1 = *(const bf16x8*)&Q[(size_t)lrow * TD + 32 + kg * 8];

    const f32x4 zero4 = {0.f, 0.f, 0.f, 0.f};
    float lacc[4];
    f32x4 oacc[4];
    #pragma unroll
    for (int r = 0; r < 4; r++) lacc[r] = 0.f;
    #pragma unroll
    for (int t = 0; t < 4; t++) oacc[t] = zero4;

    auto stage = [&](int c, int buf) {
        const int s0 = (wave & 1) * 256;
        if (wave < 2) {
            #pragma unroll
            for (int j = 0; j < 4; j++) {
                const int s = s0 + j * 64 + lane;
                const int r = s >> 3;
                const int cb = (s & 7) ^ (r & 7);
                const short* src = Kglb + (size_t)(c + r) * TD + cb * 8;
                __builtin_amdgcn_global_load_lds(
                    (GVp*)src, (LVp*)&Ks[buf][(s0 + j * 64) * 8], 16, 0, 0);
            }
        } else {
            #pragma unroll
            for (int j = 0; j < 4; j++) {
                const int s = s0 + j * 64 + lane;
                const int r = s >> 3;
                const int cb = (s & 7) ^ (r & 7);
                const short* src = Vtglb + (size_t)r * L_ + c + cb * 8;
                __builtin_amdgcn_global_load_lds(
                    (GVp*)src, (LVp*)&Vs[buf][(s0 + j * 64) * 8], 16, 0, 0);
            }
        }
    };

    const int ntiles = Sw >> 6;
    stage(0, 0);

    // p = exp2(fma(s, 0.125*log2e, -16*log2e))
    const float SC = 0.18033688011112042f;
    const float MB = -23.083120654223414f;

    for (int i = 0; i < ntiles; i++) {
        const int cur = i & 1;
        __syncthreads();
        if (i + 1 < ntiles) stage((i + 1) << 6, 1 - cur);

        const short* Kl = Ks[cur];
        const short* Vl = Vs[cur];
        const int sw = lrow & 7;

        f32x4 s[4];
        #pragma unroll
        for (int kt = 0; kt < 4; kt++) {
            const int key = kt * 16 + lrow;
            bf16x8 k0 = *(const bf16x8*)&Kl[key * 64 + ((kg     ^ sw) * 8)];
            bf16x8 k1 = *(const bf16x8*)&Kl[key * 64 + (((kg+4) ^ sw) * 8)];
            f32x4 acc = zero4;
            acc = mfma16(qf0, k0, acc);
            acc = mfma16(qf1, k1, acc);
            s[kt] = acc;
        }

        asm volatile("" ::: "memory");
        #pragma unroll
        for (int kt = 0; kt < 4; kt++) {
            #pragma unroll
            for (int r = 0; r < 4; r++) {
                const float p = exp2f(fmaf(s[kt][r], SC, MB));
                lacc[r] += p;
                myP[(kg * 4 + r) * 72 + kt * 16 + lrow] = f2bfs(p);
            }
        }
        asm volatile("s_waitcnt lgkmcnt(0)" ::: "memory");
        const bf16x8 pf0 = *(const bf16x8*)&myP[lrow * 72 + kg * 8];
        const bf16x8 pf1 = *(const bf16x8*)&myP[lrow * 72 + 32 + kg * 8];

        #pragma unroll
        for (int t = 0; t < 4; t++) {
            const int vd = t * 16 + lrow;
            bf16x8 v0 = *(const bf16x8*)&Vl[vd * 64 + ((kg     ^ sw) * 8)];
            bf16x8 v1 = *(const bf16x8*)&Vl[vd * 64 + (((kg+4) ^ sw) * 8)];
            oacc[t] = mfma16(pf0, v0, oacc[t]);
            oacc[t] = mfma16(pf1, v1, oacc[t]);
        }
    }

    #pragma unroll
    for (int off = 1; off < 16; off <<= 1)
        #pragma unroll
        for (int r = 0; r < 4; r++)
            lacc[r] += __shfl_xor(lacc[r], off, 64);

    #pragma unroll
    for (int t = 0; t < 4; t++) {
        #pragma unroll
        for (int r = 0; r < 4; r++) {
            const int row = q0 + kg * 4 + r;
            const int col = h * HD_ + t * 16 + lrow;
            o[(size_t)row * D_ + col] =
                __float2bfloat16(lclamp(oacc[t][r] / lacc[r], 1.0e4f));
        }
    }
}

// ---------------------------------------------------------------------------
extern "C" void kernel_launch(void* const* d_in, const int* in_sizes, int n_in,
                              void* d_out, int out_size, void* d_ws, size_t ws_size,
                              hipStream_t stream)
{
    const float* x   = (const float*)d_in[0];
    const float* rf  = (const float*)d_in[1];
    const float* wwi = (const float*)d_in[2];
    const float* wbi = (const float*)d_in[3];
    const float* wwo = (const float*)d_in[4];
    const float* wbo = (const float*)d_in[5];
    const float* fwi = (const float*)d_in[6];
    const float* fbi = (const float*)d_in[7];
    const float* fwo = (const float*)d_in[8];
    const float* fbo = (const float*)d_in[9];

    char* ws = (char*)d_ws;
    __hip_bfloat16* qkv = (__hip_bfloat16*)(ws);                 // [L,3D] 24 MiB
    __hip_bfloat16* ob  = (__hip_bfloat16*)(ws + (24u << 20));   // [L,D]   8 MiB
    __hip_bfloat16* xsc = (__hip_bfloat16*)d_out;                // [L,D] bf16 scratch
    __hip_bfloat16* Vt  = (__hip_bfloat16*)d_out;                // [H,HD,L] bf16

    const size_t MB1 = 1u << 20;
    // bw=1: bf16 weights pre-converted into big workspace; bw=0: fp32 W
    // staged directly in the GEMM (zero extra memory).
    const int bw = (ws_size >= 104 * MB1) ? 1 : 0;

    __hip_bfloat16* wwib = (__hip_bfloat16*)(ws + 32 * MB1);
    __hip_bfloat16* wwob = (__hip_bfloat16*)(ws + 80 * MB1);
    __hip_bfloat16* fwib = (__hip_bfloat16*)(ws + 96 * MB1);
    __hip_bfloat16* fwob = (__hip_bfloat16*)(ws + 102 * MB1);
    if (bw) {
        wcvt_all<<<dim3(36864), 256, 0, stream>>>(
            wwi, wwo, fwi, fwo, wwib, wwob, fwib, fwob);
    }

    // 1. rotary add -> x1 (bf16)
    rotary_k<<<dim3(L_ * D_ / 256), 256, 0, stream>>>(x, rf, xsc);

    // 2. per-window qkv = x1 @ win_w_in^T + win_b_in
    if (bw) gemm_u<0><<<dim3(TD / 128, L_ / 128), 256, 0, stream>>>(
        xsc, wwib, wbi, nullptr, nullptr, 0, qkv, nullptr, TD, TD * D_, TD);
    else    gemm_u<1><<<dim3(TD / 128, L_ / 128), 256, 0, stream>>>(
        xsc, wwi,  wbi, nullptr, nullptr, 0, qkv, nullptr, TD, TD * D_, TD);

    // 2b. V transpose
    transpose_v<<<dim3(L_ / 64, H_), 256, 0, stream>>>(qkv, Vt);

    // 3. windowed attention (Sw = 512)
    attn_k<<<dim3(WIN_ / 64, H_, NW_), 256, 0, stream>>>(qkv, Vt, ob, WIN_);

    // 4. x2 = (x + rotary, exact fp32) + o @ win_w_out^T + win_b_out
    if (bw) gemm_u<0><<<dim3(D_ / 128, L_ / 128), 256, 0, stream>>>(
        ob, wwob, wbo, x, rf, 1, xsc, nullptr, D_, D_ * D_, D_);
    else    gemm_u<1><<<dim3(D_ / 128, L_ / 128), 256, 0, stream>>>(
        ob, wwo,  wbo, x, rf, 1, xsc, nullptr, D_, D_ * D_, D_);

    // 5. final qkv = x2 @ fin_w_in^T + fin_b_in
    if (bw) gemm_u<0><<<dim3(TD / 128, L_ / 128), 256, 0, stream>>>(
        xsc, fwib, fbi, nullptr, nullptr, 0, qkv, nullptr, TD, 0, 0);
    else    gemm_u<1><<<dim3(TD / 128, L_ / 128), 256, 0, stream>>>(
        xsc, fwi,  fbi, nullptr, nullptr, 0, qkv, nullptr, TD, 0, 0);

    // 5b. V transpose
    transpose_v<<<dim3(L_ / 64, H_), 256, 0, stream>>>(qkv, Vt);

    // 6. global attention (Sw = 4096)
    attn_k<<<dim3(L_ / 64, H_, 1), 256, 0, stream>>>(qkv, Vt, ob, L_);

    // 7. out = o @ fin_w_out^T + fin_b_out  -> d_out (fp32, final)
    if (bw) gemm_u<0><<<dim3(D_ / 128, L_ / 128), 256, 0, stream>>>(
        ob, fwob, fbo, nullptr, nullptr, 0, nullptr, (float*)d_out, D_, 0, 0);
    else    gemm_u<1><<<dim3(D_ / 128, L_ / 128), 256, 0, stream>>>(
        ob, fwo,  fbo, nullptr, nullptr, 0, nullptr, (float*)d_out, D_, 0, 0);
}

// Round 4
// 594.430 us; speedup vs baseline: 1.2252x; 1.1263x over previous
//
#include <hip/hip_runtime.h>
#include <hip/hip_bf16.h>

#define L_ 4096
#define D_ 1024
#define H_ 16
#define HD_ 64
#define NW_ 8
#define WIN_ 512
#define TD (3*D_)

typedef __attribute__((ext_vector_type(8))) short bf16x8;
typedef __attribute__((ext_vector_type(4))) float f32x4;

typedef __attribute__((address_space(1))) const void GVp;
typedef __attribute__((address_space(3))) void LVp;

__device__ __forceinline__ f32x4 mfma16(bf16x8 a, bf16x8 b, f32x4 c) {
    return __builtin_amdgcn_mfma_f32_16x16x32_bf16(a, b, c, 0, 0, 0);
}

__device__ __forceinline__ short f2bfs(float f) {
    __hip_bfloat16 h = __float2bfloat16(f);
    return *reinterpret_cast<short*>(&h);
}

__device__ __forceinline__ float lclamp(float v, float c) {
    return fminf(fmaxf(v, -c), c);
}

// rotary additive term for (seq pos l, feature d), exact fp32
__device__ __forceinline__ float rot_add(const float* rf, int l, int d) {
    const int j = d & 511;
    const float r = rf[j];
    const float inv = exp2f((float)j * 0.02595256324130752f); // 10000^(j/512)
    const float ang = r * (float)l / inv;
    return (d < 512) ? cosf(ang) : sinf(ang);
}

// ---------------------------------------------------------------------------
__global__ __launch_bounds__(256) void rotary_k(
    const float* __restrict__ x,
    const float* __restrict__ rf,
    __hip_bfloat16* __restrict__ x1b)
{
    const int idx = blockIdx.x * 256 + threadIdx.x;   // over L*D
    const int l = idx >> 10;
    const int d = idx & 1023;
    const float v = x[idx] + rot_add(rf, l, d);
    x1b[idx] = __float2bfloat16(lclamp(v, 1.0e4f));
}

// ---------------------------------------------------------------------------
// fused fp32->bf16 weight convert
// ---------------------------------------------------------------------------
__global__ __launch_bounds__(256) void wcvt_all(
    const float* __restrict__ w0, const float* __restrict__ w1,
    const float* __restrict__ w2, const float* __restrict__ w3,
    __hip_bfloat16* __restrict__ o0, __hip_bfloat16* __restrict__ o1,
    __hip_bfloat16* __restrict__ o2, __hip_bfloat16* __restrict__ o3)
{
    const unsigned i = (blockIdx.x * 256u + threadIdx.x) * 4u;
    const float* s; __hip_bfloat16* d; unsigned j;
    if (i < 25165824u)      { s = w0; d = o0; j = i; }
    else if (i < 33554432u) { s = w1; d = o1; j = i - 25165824u; }
    else if (i < 36700160u) { s = w2; d = o2; j = i - 33554432u; }
    else                    { s = w3; d = o3; j = i - 36700160u; }
    float4 v = *(const float4*)&s[j];
    short t[4] = {f2bfs(v.x), f2bfs(v.y), f2bfs(v.z), f2bfs(v.w)};
    *(uint2*)&d[j] = *(uint2*)t;
}

// ---------------------------------------------------------------------------
// 8-phase-style deep-pipelined GEMM (T3+T4+T5), provably race-free variant:
//   C[M,N] = A[M,1024](bf16) @ W[N,1024]^T(bf16) + bias.
// 256x256 tile, BK=32, 8 waves (2M x 4N), 512 threads.
// QUAD-buffered LDS (4 x (16KB A + 16KB W) = 128 KB), stage lead = 3 K-tiles,
// counted s_waitcnt vmcnt(8) once per K-tile (never 0 in steady state;
// tail drains 8->4->0). Two phases per K-tile, each:
//   {ds_reads ; stage half ; [vmcnt] ; s_barrier ; setprio1 ; 16 MFMA ;
//    setprio0 ; s_barrier}.
// Race-freedom: stage of tile t+3 writes buf (t+3)&3 == (t-1)&3, whose last
// reads finished before the barrier that preceded the stage issue. Counted
// vmcnt at tile t guarantees tile t+1 fully in LDS (in-order retirement).
// LDS swizzle (both-sides involution, linear gload_lds dest):
//   slot s holds (row=s>>2, grp=(s&3)^(row&3)); frag read (row,kg) at slot
//   row*4 + (kg^(row&3))  -> 2-way bank access (free).
// Accumulation: k ascending in 32-chunks — bit-identical to gemm_u.
// ---------------------------------------------------------------------------
__global__ __launch_bounds__(512) void gemm8(
    const __hip_bfloat16* __restrict__ A,
    const __hip_bfloat16* __restrict__ Wb,
    const float* __restrict__ bias,
    __hip_bfloat16* __restrict__ Cb,
    int N, int wStrideW, int wStrideB)
{
    // XCD-aware bijective swizzle (n-major chunks per XCD)
    int bn = blockIdx.x, bm = blockIdx.y;
    {
        const int gx = gridDim.x, gy = gridDim.y;
        const int nblk = gx * gy;
        if ((nblk & 7) == 0) {
            const int lid = blockIdx.y * gx + blockIdx.x;
            const int per = nblk >> 3;
            const int t = (lid & 7) * per + (lid >> 3);
            bn = t / gy;
            bm = t - bn * gy;
        }
    }
    const int m0 = bm * 256;
    const int n0 = bn * 256;
    const int win = m0 / WIN_;
    const short* Wp = (const short*)Wb + (size_t)win * (size_t)wStrideW;
    const float* Bp = bias + (size_t)win * (size_t)wStrideB;

    __shared__ __align__(16) short As[4][256 * 32];   // 64 KB
    __shared__ __align__(16) short Bs[4][256 * 32];   // 64 KB

    const int tid  = threadIdx.x;
    const int lane = tid & 63;
    const int wave = tid >> 6;
    const int lrow = lane & 15;
    const int kg   = lane >> 4;
    const int wrow = (wave >> 2) * 128;   // 0 / 128
    const int wcol = (wave & 3) * 64;     // 0 / 64 / 128 / 192

    // staging: 1024 slots of 16B per tile; thread covers slots tid, tid+512
    const int sl0 = tid,       r0_ = sl0 >> 2, g0_ = (sl0 & 3) ^ (r0_ & 3);
    const int sl1 = tid + 512, r1_ = sl1 >> 2, g1_ = (sl1 & 3) ^ (r1_ & 3);
    const short* Asrc0 = (const short*)A + (size_t)(m0 + r0_) * D_ + g0_ * 8;
    const short* Asrc1 = (const short*)A + (size_t)(m0 + r1_) * D_ + g1_ * 8;
    const short* Wsrc0 = Wp + (size_t)(n0 + r0_) * D_ + g0_ * 8;
    const short* Wsrc1 = Wp + (size_t)(n0 + r1_) * D_ + g1_ * 8;

    auto stageA = [&](int t, int b) {
        __builtin_amdgcn_global_load_lds((GVp*)(Asrc0 + t * 32), (LVp*)&As[b][wave * 512], 16, 0, 0);
        __builtin_amdgcn_global_load_lds((GVp*)(Asrc1 + t * 32), (LVp*)&As[b][4096 + wave * 512], 16, 0, 0);
    };
    auto stageB = [&](int t, int b) {
        __builtin_amdgcn_global_load_lds((GVp*)(Wsrc0 + t * 32), (LVp*)&Bs[b][wave * 512], 16, 0, 0);
        __builtin_amdgcn_global_load_lds((GVp*)(Wsrc1 + t * 32), (LVp*)&Bs[b][4096 + wave * 512], 16, 0, 0);
    };

    // frag LDS short-offsets (swizzled read side of the involution)
    int aoff[8], boff[4];
    #pragma unroll
    for (int i = 0; i < 8; i++) {
        const int row = wrow + i * 16 + lrow;
        aoff[i] = (row * 4 + (kg ^ (row & 3))) * 8;
    }
    #pragma unroll
    for (int j = 0; j < 4; j++) {
        const int row = wcol + j * 16 + lrow;
        boff[j] = (row * 4 + (kg ^ (row & 3))) * 8;
    }

    const f32x4 zero4 = {0.f, 0.f, 0.f, 0.f};
    f32x4 acc[8][4];
    #pragma unroll
    for (int i = 0; i < 8; i++)
        #pragma unroll
        for (int j = 0; j < 4; j++) acc[i][j] = zero4;

    // prologue: stage tiles 0,1,2; wait until tile 0 landed (12 issued, <=8)
    stageA(0, 0); stageB(0, 0);
    stageA(1, 1); stageB(1, 1);
    stageA(2, 2); stageB(2, 2);
    asm volatile("s_waitcnt vmcnt(8)" ::: "memory");
    __builtin_amdgcn_s_barrier();

    const int NT = D_ / 32;               // 32 K-tiles
    #pragma unroll 1
    for (int t = 0; t < NT; ++t) {
        const int cb = t & 3;
        const short* Ab = As[cb];
        const short* Bb = Bs[cb];
        bf16x8 af[4], bfr[4];

        // ---- phase 0: m-frags 0..3 x all n-frags ----
        #pragma unroll
        for (int j = 0; j < 4; j++) bfr[j] = *(const bf16x8*)&Bb[boff[j]];
        #pragma unroll
        for (int i = 0; i < 4; i++) af[i] = *(const bf16x8*)&Ab[aoff[i]];
        if (t + 3 < NT) stageA(t + 3, (t + 3) & 3);
        __builtin_amdgcn_s_barrier();
        __builtin_amdgcn_s_setprio(1);
        #pragma unroll
        for (int i = 0; i < 4; i++)
            #pragma unroll
            for (int j = 0; j < 4; j++)
                acc[i][j] = mfma16(af[i], bfr[j], acc[i][j]);
        __builtin_amdgcn_s_setprio(0);
        __builtin_amdgcn_s_barrier();

        // ---- phase 1: m-frags 4..7 x all n-frags ----
        #pragma unroll
        for (int i = 0; i < 4; i++) af[i] = *(const bf16x8*)&Ab[aoff[4 + i]];
        if (t + 3 < NT) stageB(t + 3, (t + 3) & 3);
        // counted wait: tile t+1 fully landed; tiles t+2,t+3 stay in flight
        if (t <= NT - 4)      asm volatile("s_waitcnt vmcnt(8)" ::: "memory");
        else if (t == NT - 3) asm volatile("s_waitcnt vmcnt(4)" ::: "memory");
        else if (t == NT - 2) asm volatile("s_waitcnt vmcnt(0)" ::: "memory");
        __builtin_amdgcn_s_barrier();
        __builtin_amdgcn_s_setprio(1);
        #pragma unroll
        for (int i = 0; i < 4; i++)
            #pragma unroll
            for (int j = 0; j < 4; j++)
                acc[4 + i][j] = mfma16(af[i], bfr[j], acc[4 + i][j]);
        __builtin_amdgcn_s_setprio(0);
        __builtin_amdgcn_s_barrier();
    }

    // epilogue: C/D layout row = kg*4 + r, col = lrow per 16x16 tile
    #pragma unroll
    for (int j = 0; j < 4; j++) {
        const int col = n0 + wcol + j * 16 + lrow;
        const float bv = Bp[col];
        #pragma unroll
        for (int i = 0; i < 8; i++) {
            #pragma unroll
            for (int r = 0; r < 4; r++) {
                const int row = m0 + wrow + i * 16 + kg * 4 + r;
                const float v = lclamp(acc[i][j][r] + bv, 1.0e4f);
                Cb[(size_t)row * N + col] = __float2bfloat16(v);
            }
        }
    }
}

// ---------------------------------------------------------------------------
// Unified 128x128 GEMM (2-phase, m97 structure) — used for the two small
// projection GEMMs (grid 256 = 1 block/CU) and as the fp32-W fallback.
// ---------------------------------------------------------------------------
template<int WF32>
__global__ __launch_bounds__(256) void gemm_u(
    const __hip_bfloat16* __restrict__ A,
    const void* __restrict__ Wv,
    const float* __restrict__ bias,
    const float* __restrict__ xin,
    const float* __restrict__ rf,
    int residMode,
    __hip_bfloat16* __restrict__ Cb,
    float* __restrict__ Cf,
    int N, int wStrideW, int wStrideB)
{
    int bn = blockIdx.x, bm = blockIdx.y;
    {
        const int gx = gridDim.x, gy = gridDim.y;
        const int nblk = gx * gy;
        if ((nblk & 7) == 0) {
            const int lid = blockIdx.y * gx + blockIdx.x;
            const int per = nblk >> 3;
            const int t = (lid & 7) * per + (lid >> 3);
            bn = t / gy;
            bm = t - bn * gy;
        }
    }
    const int m0 = bm * 128;
    const int n0 = bn * 128;
    const int win = m0 / WIN_;

    const short* Wb = (const short*)Wv + (WF32 ? 0 : (size_t)win * (size_t)wStrideW);
    const float* Wf = (const float*)Wv + (WF32 ? (size_t)win * (size_t)wStrideW : 0);
    const float* Bp = bias + (size_t)win * (size_t)wStrideB;

    __shared__ __align__(16) short As[2][128 * 32];
    __shared__ __align__(16) short Bs[2][WF32 ? 128 * 64 : 128 * 32];

    const int tid  = threadIdx.x;
    const int lane = tid & 63;
    const int wave = tid >> 6;
    const int wm = (wave & 1) * 64;
    const int wn = (wave >> 1) * 64;
    const int lrow = lane & 15;
    const int kg   = lane >> 4;

    const int sA0 = tid,        rA0 = sA0 >> 2, gA0 = (sA0 & 3) ^ ((rA0 >> 1) & 3);
    const int sA1 = tid + 256,  rA1 = sA1 >> 2, gA1 = (sA1 & 3) ^ ((rA1 >> 1) & 3);
    const short* Asrc0 = (const short*)A + (size_t)(m0 + rA0) * D_ + gA0 * 8;
    const short* Asrc1 = (const short*)A + (size_t)(m0 + rA1) * D_ + gA1 * 8;

    const short* Wsrc0 = Wb + (size_t)(n0 + rA0) * D_ + gA0 * 8;
    const short* Wsrc1 = Wb + (size_t)(n0 + rA1) * D_ + gA1 * 8;

    const float* Fsrc[4];
    if (WF32) {
        #pragma unroll
        for (int j = 0; j < 4; j++) {
            const int s = tid + 256 * j;
            const int row = s >> 3;
            const int g8 = (s & 7) ^ (row & 7);
            Fsrc[j] = Wf + (size_t)(n0 + row) * D_ + g8 * 4;
        }
    }

    auto stage = [&](int k0, int buf) {
        __builtin_amdgcn_global_load_lds((GVp*)(Asrc0 + k0), (LVp*)&As[buf][wave * 512],        16, 0, 0);
        __builtin_amdgcn_global_load_lds((GVp*)(Asrc1 + k0), (LVp*)&As[buf][2048 + wave * 512], 16, 0, 0);
        if (WF32) {
            #pragma unroll
            for (int j = 0; j < 4; j++)
                __builtin_amdgcn_global_load_lds((GVp*)(Fsrc[j] + k0), (LVp*)&Bs[buf][j * 2048 + wave * 512], 16, 0, 0);
        } else {
            __builtin_amdgcn_global_load_lds((GVp*)(Wsrc0 + k0), (LVp*)&Bs[buf][wave * 512],        16, 0, 0);
            __builtin_amdgcn_global_load_lds((GVp*)(Wsrc1 + k0), (LVp*)&Bs[buf][2048 + wave * 512], 16, 0, 0);
        }
    };

    const f32x4 zero4 = {0.f, 0.f, 0.f, 0.f};
    f32x4 acc[4][4];
    #pragma unroll
    for (int i = 0; i < 4; i++)
        #pragma unroll
        for (int jj = 0; jj < 4; jj++) acc[i][jj] = zero4;

    stage(0, 0);
    const int nsteps = D_ / 32;
    for (int i = 0; i < nsteps; i++) {
        const int cur = i & 1;
        __syncthreads();
        if (i + 1 < nsteps) stage((i + 1) * 32, 1 - cur);

        bf16x8 af[4], bfr[4];
        #pragma unroll
        for (int ii = 0; ii < 4; ii++) {
            const int ar_ = wm + ii * 16 + lrow;
            af[ii] = *(const bf16x8*)&As[cur][ar_ * 32 + ((kg ^ ((ar_ >> 1) & 3)) * 8)];
        }
        #pragma unroll
        for (int jj = 0; jj < 4; jj++) {
            const int wr_ = wn + jj * 16 + lrow;
            if (WF32) {
                const float4 wlo = *(const float4*)&Bs[cur][wr_ * 64 + (((2 * kg)     ^ (wr_ & 7)) * 8)];
                const float4 whi = *(const float4*)&Bs[cur][wr_ * 64 + (((2 * kg + 1) ^ (wr_ & 7)) * 8)];
                short t[8] = {f2bfs(wlo.x), f2bfs(wlo.y), f2bfs(wlo.z), f2bfs(wlo.w),
                              f2bfs(whi.x), f2bfs(whi.y), f2bfs(whi.z), f2bfs(whi.w)};
                bfr[jj] = *(const bf16x8*)t;
            } else {
                bfr[jj] = *(const bf16x8*)&Bs[cur][wr_ * 32 + ((kg ^ ((wr_ >> 1) & 3)) * 8)];
            }
        }
        #pragma unroll
        for (int ii = 0; ii < 4; ii++)
            #pragma unroll
            for (int jj = 0; jj < 4; jj++)
                acc[ii][jj] = mfma16(af[ii], bfr[jj], acc[ii][jj]);
    }

    #pragma unroll
    for (int jj = 0; jj < 4; jj++) {
        const int col = n0 + wn + jj * 16 + lrow;
        const float bv = Bp[col];
        #pragma unroll
        for (int i = 0; i < 4; i++) {
            #pragma unroll
            for (int r = 0; r < 4; r++) {
                const int row = m0 + wm + i * 16 + kg * 4 + r;
                float v = acc[i][jj][r] + bv;
                if (residMode) {
                    v += xin[(size_t)row * D_ + col] + rot_add(rf, row, col);
                }
                v = lclamp(v, 1.0e4f);
                if (Cf) Cf[(size_t)row * N + col] = v;
                else    Cb[(size_t)row * N + col] = __float2bfloat16(v);
            }
        }
    }
}

// ---------------------------------------------------------------------------
// Transpose V out of qkv: Vt[h][vd][l] = qkv[l][2*D + h*64 + vd]
// ---------------------------------------------------------------------------
__global__ __launch_bounds__(256) void transpose_v(
    const __hip_bfloat16* __restrict__ qkv,
    __hip_bfloat16* __restrict__ Vt)
{
    __shared__ __align__(16) short Ts[64 * 72];
    const int t = threadIdx.x;
    const int l0 = blockIdx.x * 64;
    const int h = blockIdx.y;
    #pragma unroll
    for (int p = 0; p < 2; p++) {
        const int idx = p * 256 + t;
        const int key = idx >> 3, part = idx & 7;
        *(uint4*)&Ts[key * 72 + part * 8] =
            *(const uint4*)&qkv[(size_t)(l0 + key) * TD + 2 * D_ + h * HD_ + part * 8];
    }
    __syncthreads();
    #pragma unroll
    for (int p = 0; p < 2; p++) {
        const int idx = p * 256 + t;
        const int vd = idx >> 3, part = idx & 7;
        short tmp[8];
        #pragma unroll
        for (int j = 0; j < 8; j++) tmp[j] = Ts[(part * 8 + j) * 72 + vd];
        *(uint4*)&Vt[(size_t)(h * HD_ + vd) * L_ + l0 + part * 8] = *(uint4*)tmp;
    }
}

// ---------------------------------------------------------------------------
// Flash attention v4 (fixed-max streaming softmax), XCD block swizzle.
// ---------------------------------------------------------------------------
__global__ __launch_bounds__(256, 3) void attn_k(
    const __hip_bfloat16* __restrict__ qkv,
    const __hip_bfloat16* __restrict__ Vt,
    __hip_bfloat16* __restrict__ o,
    int Sw)
{
    const int tid  = threadIdx.x;
    const int lane = tid & 63;
    const int wave = tid >> 6;
    const int lrow = lane & 15;
    const int kg   = lane >> 4;

    int bx = blockIdx.x, by = blockIdx.y, bz = blockIdx.z;
    {
        const int gx = gridDim.x, gy = gridDim.y, gz = gridDim.z;
        const int nblk = gx * gy * gz;
        if ((nblk & 7) == 0) {
            const int lid = (blockIdx.z * gy + blockIdx.y) * gx + blockIdx.x;
            const int per = nblk >> 3;
            const int t = (lid & 7) * per + (lid >> 3);
            bx = t % gx;
            const int rest = t / gx;
            by = rest % gy;
            bz = rest / gy;
        }
    }
    const int h = by;
    const int wbase = bz * Sw;
    const int q0 = wbase + bx * 64 + wave * 16;

    const short* Kglb = reinterpret_cast<const short*>(qkv)
                        + (size_t)wbase * TD + D_ + h * HD_;
    const short* Vtglb = reinterpret_cast<const short*>(Vt)
                         + (size_t)h * HD_ * L_ + wbase;
    const __hip_bfloat16* Q = qkv + (size_t)q0 * TD + h * HD_;

    __shared__ __align__(16) short Ks[2][64 * 64];
    __shared__ __align__(16) short Vs[2][64 * 64];
    __shared__ __align__(16) short Ps[4][16 * 72];
    short* myP = &Ps[wave][0];

    const bf16x8 qf0 = *(const bf16x8*)&Q[(size_t)lrow * TD + kg * 8];
    const bf16x8 qf1 = *(const bf16x8*)&Q[(size_t)lrow * TD + 32 + kg * 8];

    const f32x4 zero4 = {0.f, 0.f, 0.f, 0.f};
    float lacc[4];
    f32x4 oacc[4];
    #pragma unroll
    for (int r = 0; r < 4; r++) lacc[r] = 0.f;
    #pragma unroll
    for (int t = 0; t < 4; t++) oacc[t] = zero4;

    auto stage = [&](int c, int buf) {
        const int s0 = (wave & 1) * 256;
        if (wave < 2) {
            #pragma unroll
            for (int j = 0; j < 4; j++) {
                const int s = s0 + j * 64 + lane;
                const int r = s >> 3;
                const int cb = (s & 7) ^ (r & 7);
                const short* src = Kglb + (size_t)(c + r) * TD + cb * 8;
                __builtin_amdgcn_global_load_lds(
                    (GVp*)src, (LVp*)&Ks[buf][(s0 + j * 64) * 8], 16, 0, 0);
            }
        } else {
            #pragma unroll
            for (int j = 0; j < 4; j++) {
                const int s = s0 + j * 64 + lane;
                const int r = s >> 3;
                const int cb = (s & 7) ^ (r & 7);
                const short* src = Vtglb + (size_t)r * L_ + c + cb * 8;
                __builtin_amdgcn_global_load_lds(
                    (GVp*)src, (LVp*)&Vs[buf][(s0 + j * 64) * 8], 16, 0, 0);
            }
        }
    };

    const int ntiles = Sw >> 6;
    stage(0, 0);

    // p = exp2(fma(s, 0.125*log2e, -16*log2e))
    const float SC = 0.18033688011112042f;
    const float MB = -23.083120654223414f;

    for (int i = 0; i < ntiles; i++) {
        const int cur = i & 1;
        __syncthreads();
        if (i + 1 < ntiles) stage((i + 1) << 6, 1 - cur);

        const short* Kl = Ks[cur];
        const short* Vl = Vs[cur];
        const int sw = lrow & 7;

        f32x4 s[4];
        #pragma unroll
        for (int kt = 0; kt < 4; kt++) {
            const int key = kt * 16 + lrow;
            bf16x8 k0 = *(const bf16x8*)&Kl[key * 64 + ((kg     ^ sw) * 8)];
            bf16x8 k1 = *(const bf16x8*)&Kl[key * 64 + (((kg+4) ^ sw) * 8)];
            f32x4 acc = zero4;
            acc = mfma16(qf0, k0, acc);
            acc = mfma16(qf1, k1, acc);
            s[kt] = acc;
        }

        asm volatile("" ::: "memory");
        #pragma unroll
        for (int kt = 0; kt < 4; kt++) {
            #pragma unroll
            for (int r = 0; r < 4; r++) {
                const float p = exp2f(fmaf(s[kt][r], SC, MB));
                lacc[r] += p;
                myP[(kg * 4 + r) * 72 + kt * 16 + lrow] = f2bfs(p);
            }
        }
        asm volatile("s_waitcnt lgkmcnt(0)" ::: "memory");
        const bf16x8 pf0 = *(const bf16x8*)&myP[lrow * 72 + kg * 8];
        const bf16x8 pf1 = *(const bf16x8*)&myP[lrow * 72 + 32 + kg * 8];

        #pragma unroll
        for (int t = 0; t < 4; t++) {
            const int vd = t * 16 + lrow;
            bf16x8 v0 = *(const bf16x8*)&Vl[vd * 64 + ((kg     ^ sw) * 8)];
            bf16x8 v1 = *(const bf16x8*)&Vl[vd * 64 + (((kg+4) ^ sw) * 8)];
            oacc[t] = mfma16(pf0, v0, oacc[t]);
            oacc[t] = mfma16(pf1, v1, oacc[t]);
        }
    }

    #pragma unroll
    for (int off = 1; off < 16; off <<= 1)
        #pragma unroll
        for (int r = 0; r < 4; r++)
            lacc[r] += __shfl_xor(lacc[r], off, 64);

    #pragma unroll
    for (int t = 0; t < 4; t++) {
        #pragma unroll
        for (int r = 0; r < 4; r++) {
            const int row = q0 + kg * 4 + r;
            const int col = h * HD_ + t * 16 + lrow;
            o[(size_t)row * D_ + col] =
                __float2bfloat16(lclamp(oacc[t][r] / lacc[r], 1.0e4f));
        }
    }
}

// ---------------------------------------------------------------------------
extern "C" void kernel_launch(void* const* d_in, const int* in_sizes, int n_in,
                              void* d_out, int out_size, void* d_ws, size_t ws_size,
                              hipStream_t stream)
{
    const float* x   = (const float*)d_in[0];
    const float* rf  = (const float*)d_in[1];
    const float* wwi = (const float*)d_in[2];
    const float* wbi = (const float*)d_in[3];
    const float* wwo = (const float*)d_in[4];
    const float* wbo = (const float*)d_in[5];
    const float* fwi = (const float*)d_in[6];
    const float* fbi = (const float*)d_in[7];
    const float* fwo = (const float*)d_in[8];
    const float* fbo = (const float*)d_in[9];

    char* ws = (char*)d_ws;
    __hip_bfloat16* qkv = (__hip_bfloat16*)(ws);                 // [L,3D] 24 MiB
    __hip_bfloat16* ob  = (__hip_bfloat16*)(ws + (24u << 20));   // [L,D]   8 MiB
    __hip_bfloat16* xsc = (__hip_bfloat16*)d_out;                // [L,D] bf16 scratch
    __hip_bfloat16* Vt  = (__hip_bfloat16*)d_out;                // [H,HD,L] bf16

    const size_t MB1 = 1u << 20;
    const int bw = (ws_size >= 104 * MB1) ? 1 : 0;

    __hip_bfloat16* wwib = (__hip_bfloat16*)(ws + 32 * MB1);
    __hip_bfloat16* wwob = (__hip_bfloat16*)(ws + 80 * MB1);
    __hip_bfloat16* fwib = (__hip_bfloat16*)(ws + 96 * MB1);
    __hip_bfloat16* fwob = (__hip_bfloat16*)(ws + 102 * MB1);
    if (bw) {
        wcvt_all<<<dim3(36864), 256, 0, stream>>>(
            wwi, wwo, fwi, fwo, wwib, wwob, fwib, fwob);
    }

    // 1. rotary add -> x1 (bf16)
    rotary_k<<<dim3(L_ * D_ / 256), 256, 0, stream>>>(x, rf, xsc);

    // 2. per-window qkv = x1 @ win_w_in^T + win_b_in   (8-phase 256^2)
    if (bw) gemm8<<<dim3(TD / 256, L_ / 256), 512, 0, stream>>>(
        xsc, wwib, wbi, qkv, TD, TD * D_, TD);
    else    gemm_u<1><<<dim3(TD / 128, L_ / 128), 256, 0, stream>>>(
        xsc, wwi,  wbi, nullptr, nullptr, 0, qkv, nullptr, TD, TD * D_, TD);

    // 2b. V transpose
    transpose_v<<<dim3(L_ / 64, H_), 256, 0, stream>>>(qkv, Vt);

    // 3. windowed attention (Sw = 512)
    attn_k<<<dim3(WIN_ / 64, H_, NW_), 256, 0, stream>>>(qkv, Vt, ob, WIN_);

    // 4. x2 = (x + rotary, exact fp32) + o @ win_w_out^T + win_b_out
    if (bw) gemm_u<0><<<dim3(D_ / 128, L_ / 128), 256, 0, stream>>>(
        ob, wwob, wbo, x, rf, 1, xsc, nullptr, D_, D_ * D_, D_);
    else    gemm_u<1><<<dim3(D_ / 128, L_ / 128), 256, 0, stream>>>(
        ob, wwo,  wbo, x, rf, 1, xsc, nullptr, D_, D_ * D_, D_);

    // 5. final qkv = x2 @ fin_w_in^T + fin_b_in   (8-phase 256^2)
    if (bw) gemm8<<<dim3(TD / 256, L_ / 256), 512, 0, stream>>>(
        xsc, fwib, fbi, qkv, TD, 0, 0);
    else    gemm_u<1><<<dim3(TD / 128, L_ / 128), 256, 0, stream>>>(
        xsc, fwi,  fbi, nullptr, nullptr, 0, qkv, nullptr, TD, 0, 0);

    // 5b. V transpose
    transpose_v<<<dim3(L_ / 64, H_), 256, 0, stream>>>(qkv, Vt);

    // 6. global attention (Sw = 4096)
    attn_k<<<dim3(L_ / 64, H_, 1), 256, 0, stream>>>(qkv, Vt, ob, L_);

    // 7. out = o @ fin_w_out^T + fin_b_out  -> d_out (fp32, final)
    if (bw) gemm_u<0><<<dim3(D_ / 128, L_ / 128), 256, 0, stream>>>(
        ob, fwob, fbo, nullptr, nullptr, 0, nullptr, (float*)d_out, D_, 0, 0);
    else    gemm_u<1><<<dim3(D_ / 128, L_ / 128), 256, 0, stream>>>(
        ob, fwo,  fbo, nullptr, nullptr, 0, nullptr, (float*)d_out, D_, 0, 0);
}

// Round 6
// 556.219 us; speedup vs baseline: 1.3094x; 1.0687x over previous
//
#include <hip/hip_runtime.h>
#include <hip/hip_bf16.h>

#define L_ 4096
#define D_ 1024
#define H_ 16
#define HD_ 64
#define NW_ 8
#define WIN_ 512
#define TD (3*D_)

typedef __attribute__((ext_vector_type(8))) short bf16x8;
typedef __attribute__((ext_vector_type(4))) float f32x4;

typedef __attribute__((address_space(1))) const void GVp;
typedef __attribute__((address_space(3))) void LVp;

__device__ __forceinline__ f32x4 mfma16(bf16x8 a, bf16x8 b, f32x4 c) {
    return __builtin_amdgcn_mfma_f32_16x16x32_bf16(a, b, c, 0, 0, 0);
}

__device__ __forceinline__ short f2bfs(float f) {
    __hip_bfloat16 h = __float2bfloat16(f);
    return *reinterpret_cast<short*>(&h);
}

__device__ __forceinline__ float lclamp(float v, float c) {
    return fminf(fmaxf(v, -c), c);
}

// rotary additive term for (seq pos l, feature d), exact fp32
__device__ __forceinline__ float rot_add(const float* rf, int l, int d) {
    const int j = d & 511;
    const float r = rf[j];
    const float inv = exp2f((float)j * 0.02595256324130752f); // 10000^(j/512)
    const float ang = r * (float)l / inv;
    return (d < 512) ? cosf(ang) : sinf(ang);
}

// ---------------------------------------------------------------------------
__global__ __launch_bounds__(256) void rotary_k(
    const float* __restrict__ x,
    const float* __restrict__ rf,
    __hip_bfloat16* __restrict__ x1b)
{
    const int idx = blockIdx.x * 256 + threadIdx.x;   // over L*D
    const int l = idx >> 10;
    const int d = idx & 1023;
    const float v = x[idx] + rot_add(rf, l, d);
    x1b[idx] = __float2bfloat16(lclamp(v, 1.0e4f));
}

// ---------------------------------------------------------------------------
// fused fp32->bf16 weight convert
// ---------------------------------------------------------------------------
__global__ __launch_bounds__(256) void wcvt_all(
    const float* __restrict__ w0, const float* __restrict__ w1,
    const float* __restrict__ w2, const float* __restrict__ w3,
    __hip_bfloat16* __restrict__ o0, __hip_bfloat16* __restrict__ o1,
    __hip_bfloat16* __restrict__ o2, __hip_bfloat16* __restrict__ o3)
{
    const unsigned i = (blockIdx.x * 256u + threadIdx.x) * 4u;
    const float* s; __hip_bfloat16* d; unsigned j;
    if (i < 25165824u)      { s = w0; d = o0; j = i; }
    else if (i < 33554432u) { s = w1; d = o1; j = i - 25165824u; }
    else if (i < 36700160u) { s = w2; d = o2; j = i - 33554432u; }
    else                    { s = w3; d = o3; j = i - 36700160u; }
    float4 v = *(const float4*)&s[j];
    short t[4] = {f2bfs(v.x), f2bfs(v.y), f2bfs(v.z), f2bfs(v.w)};
    *(uint2*)&d[j] = *(uint2*)t;
}

// ---------------------------------------------------------------------------
// 8-phase-style deep-pipelined GEMM (T3+T4+T5), 256x256, quad-buffered LDS,
// counted vmcnt (never 0 in steady state). Unchanged from round 4.
// ---------------------------------------------------------------------------
__global__ __launch_bounds__(512) void gemm8(
    const __hip_bfloat16* __restrict__ A,
    const __hip_bfloat16* __restrict__ Wb,
    const float* __restrict__ bias,
    __hip_bfloat16* __restrict__ Cb,
    int N, int wStrideW, int wStrideB)
{
    int bn = blockIdx.x, bm = blockIdx.y;
    {
        const int gx = gridDim.x, gy = gridDim.y;
        const int nblk = gx * gy;
        if ((nblk & 7) == 0) {
            const int lid = blockIdx.y * gx + blockIdx.x;
            const int per = nblk >> 3;
            const int t = (lid & 7) * per + (lid >> 3);
            bn = t / gy;
            bm = t - bn * gy;
        }
    }
    const int m0 = bm * 256;
    const int n0 = bn * 256;
    const int win = m0 / WIN_;
    const short* Wp = (const short*)Wb + (size_t)win * (size_t)wStrideW;
    const float* Bp = bias + (size_t)win * (size_t)wStrideB;

    __shared__ __align__(16) short As[4][256 * 32];   // 64 KB
    __shared__ __align__(16) short Bs[4][256 * 32];   // 64 KB

    const int tid  = threadIdx.x;
    const int lane = tid & 63;
    const int wave = tid >> 6;
    const int lrow = lane & 15;
    const int kg   = lane >> 4;
    const int wrow = (wave >> 2) * 128;   // 0 / 128
    const int wcol = (wave & 3) * 64;     // 0 / 64 / 128 / 192

    const int sl0 = tid,       r0_ = sl0 >> 2, g0_ = (sl0 & 3) ^ (r0_ & 3);
    const int sl1 = tid + 512, r1_ = sl1 >> 2, g1_ = (sl1 & 3) ^ (r1_ & 3);
    const short* Asrc0 = (const short*)A + (size_t)(m0 + r0_) * D_ + g0_ * 8;
    const short* Asrc1 = (const short*)A + (size_t)(m0 + r1_) * D_ + g1_ * 8;
    const short* Wsrc0 = Wp + (size_t)(n0 + r0_) * D_ + g0_ * 8;
    const short* Wsrc1 = Wp + (size_t)(n0 + r1_) * D_ + g1_ * 8;

    auto stageA = [&](int t, int b) {
        __builtin_amdgcn_global_load_lds((GVp*)(Asrc0 + t * 32), (LVp*)&As[b][wave * 512], 16, 0, 0);
        __builtin_amdgcn_global_load_lds((GVp*)(Asrc1 + t * 32), (LVp*)&As[b][4096 + wave * 512], 16, 0, 0);
    };
    auto stageB = [&](int t, int b) {
        __builtin_amdgcn_global_load_lds((GVp*)(Wsrc0 + t * 32), (LVp*)&Bs[b][wave * 512], 16, 0, 0);
        __builtin_amdgcn_global_load_lds((GVp*)(Wsrc1 + t * 32), (LVp*)&Bs[b][4096 + wave * 512], 16, 0, 0);
    };

    int aoff[8], boff[4];
    #pragma unroll
    for (int i = 0; i < 8; i++) {
        const int row = wrow + i * 16 + lrow;
        aoff[i] = (row * 4 + (kg ^ (row & 3))) * 8;
    }
    #pragma unroll
    for (int j = 0; j < 4; j++) {
        const int row = wcol + j * 16 + lrow;
        boff[j] = (row * 4 + (kg ^ (row & 3))) * 8;
    }

    const f32x4 zero4 = {0.f, 0.f, 0.f, 0.f};
    f32x4 acc[8][4];
    #pragma unroll
    for (int i = 0; i < 8; i++)
        #pragma unroll
        for (int j = 0; j < 4; j++) acc[i][j] = zero4;

    stageA(0, 0); stageB(0, 0);
    stageA(1, 1); stageB(1, 1);
    stageA(2, 2); stageB(2, 2);
    asm volatile("s_waitcnt vmcnt(8)" ::: "memory");
    __builtin_amdgcn_s_barrier();

    const int NT = D_ / 32;               // 32 K-tiles
    #pragma unroll 1
    for (int t = 0; t < NT; ++t) {
        const int cb = t & 3;
        const short* Ab = As[cb];
        const short* Bb = Bs[cb];
        bf16x8 af[4], bfr[4];

        #pragma unroll
        for (int j = 0; j < 4; j++) bfr[j] = *(const bf16x8*)&Bb[boff[j]];
        #pragma unroll
        for (int i = 0; i < 4; i++) af[i] = *(const bf16x8*)&Ab[aoff[i]];
        if (t + 3 < NT) stageA(t + 3, (t + 3) & 3);
        __builtin_amdgcn_s_barrier();
        __builtin_amdgcn_s_setprio(1);
        #pragma unroll
        for (int i = 0; i < 4; i++)
            #pragma unroll
            for (int j = 0; j < 4; j++)
                acc[i][j] = mfma16(af[i], bfr[j], acc[i][j]);
        __builtin_amdgcn_s_setprio(0);
        __builtin_amdgcn_s_barrier();

        #pragma unroll
        for (int i = 0; i < 4; i++) af[i] = *(const bf16x8*)&Ab[aoff[4 + i]];
        if (t + 3 < NT) stageB(t + 3, (t + 3) & 3);
        if (t <= NT - 4)      asm volatile("s_waitcnt vmcnt(8)" ::: "memory");
        else if (t == NT - 3) asm volatile("s_waitcnt vmcnt(4)" ::: "memory");
        else if (t == NT - 2) asm volatile("s_waitcnt vmcnt(0)" ::: "memory");
        __builtin_amdgcn_s_barrier();
        __builtin_amdgcn_s_setprio(1);
        #pragma unroll
        for (int i = 0; i < 4; i++)
            #pragma unroll
            for (int j = 0; j < 4; j++)
                acc[4 + i][j] = mfma16(af[i], bfr[j], acc[4 + i][j]);
        __builtin_amdgcn_s_setprio(0);
        __builtin_amdgcn_s_barrier();
    }

    #pragma unroll
    for (int j = 0; j < 4; j++) {
        const int col = n0 + wcol + j * 16 + lrow;
        const float bv = Bp[col];
        #pragma unroll
        for (int i = 0; i < 8; i++) {
            #pragma unroll
            for (int r = 0; r < 4; r++) {
                const int row = m0 + wrow + i * 16 + kg * 4 + r;
                const float v = lclamp(acc[i][j][r] + bv, 1.0e4f);
                Cb[(size_t)row * N + col] = __float2bfloat16(v);
            }
        }
    }
}

// ---------------------------------------------------------------------------
// Unified GEMM (2-phase, m97 structure), templated output tile height:
// BM=128 (fp32-W fallback / generic) or BM=64 (small-N proj GEMMs: doubles
// the grid to 512 blocks -> 2 blocks/CU instead of 1 -> real TLP).
// ---------------------------------------------------------------------------
template<int WF32, int BM>
__global__ __launch_bounds__(256) void gemm_u(
    const __hip_bfloat16* __restrict__ A,
    const void* __restrict__ Wv,
    const float* __restrict__ bias,
    const float* __restrict__ xin,
    const float* __restrict__ rf,
    int residMode,
    __hip_bfloat16* __restrict__ Cb,
    float* __restrict__ Cf,
    int N, int wStrideW, int wStrideB)
{
    int bn = blockIdx.x, bm = blockIdx.y;
    {
        const int gx = gridDim.x, gy = gridDim.y;
        const int nblk = gx * gy;
        if ((nblk & 7) == 0) {
            const int lid = blockIdx.y * gx + blockIdx.x;
            const int per = nblk >> 3;
            const int t = (lid & 7) * per + (lid >> 3);
            bn = t / gy;
            bm = t - bn * gy;
        }
    }
    const int m0 = bm * BM;
    const int n0 = bn * 128;
    const int win = m0 / WIN_;

    const short* Wb = (const short*)Wv + (WF32 ? 0 : (size_t)win * (size_t)wStrideW);
    const float* Wf = (const float*)Wv + (WF32 ? (size_t)win * (size_t)wStrideW : 0);
    const float* Bp = bias + (size_t)win * (size_t)wStrideB;

    __shared__ __align__(16) short As[2][BM * 32];
    __shared__ __align__(16) short Bs[2][WF32 ? 128 * 64 : 128 * 32];

    const int tid  = threadIdx.x;
    const int lane = tid & 63;
    const int wave = tid >> 6;
    const int wm = (wave & 1) * (BM / 2);
    const int wn = (wave >> 1) * 64;
    const int lrow = lane & 15;
    const int kg   = lane >> 4;
    constexpr int MF = BM / 32;           // m-frags per wave

    const int sA0 = tid,        rA0 = sA0 >> 2, gA0 = (sA0 & 3) ^ ((rA0 >> 1) & 3);
    const int sA1 = tid + 256,  rA1 = sA1 >> 2, gA1 = (sA1 & 3) ^ ((rA1 >> 1) & 3);
    const short* Asrc0 = (const short*)A + (size_t)(m0 + rA0) * D_ + gA0 * 8;
    const short* Asrc1 = (const short*)A + (size_t)(m0 + (BM == 128 ? rA1 : 0)) * D_ + gA1 * 8;

    const short* Wsrc0 = Wb + (size_t)(n0 + rA0) * D_ + gA0 * 8;
    const short* Wsrc1 = Wb + (size_t)(n0 + rA1) * D_ + gA1 * 8;

    const float* Fsrc[4];
    if (WF32) {
        #pragma unroll
        for (int j = 0; j < 4; j++) {
            const int s = tid + 256 * j;
            const int row = s >> 3;
            const int g8 = (s & 7) ^ (row & 7);
            Fsrc[j] = Wf + (size_t)(n0 + row) * D_ + g8 * 4;
        }
    }

    auto stage = [&](int k0, int buf) {
        __builtin_amdgcn_global_load_lds((GVp*)(Asrc0 + k0), (LVp*)&As[buf][wave * 512], 16, 0, 0);
        if (BM == 128)
            __builtin_amdgcn_global_load_lds((GVp*)(Asrc1 + k0), (LVp*)&As[buf][2048 + wave * 512], 16, 0, 0);
        if (WF32) {
            #pragma unroll
            for (int j = 0; j < 4; j++)
                __builtin_amdgcn_global_load_lds((GVp*)(Fsrc[j] + k0), (LVp*)&Bs[buf][j * 2048 + wave * 512], 16, 0, 0);
        } else {
            __builtin_amdgcn_global_load_lds((GVp*)(Wsrc0 + k0), (LVp*)&Bs[buf][wave * 512],        16, 0, 0);
            __builtin_amdgcn_global_load_lds((GVp*)(Wsrc1 + k0), (LVp*)&Bs[buf][2048 + wave * 512], 16, 0, 0);
        }
    };

    const f32x4 zero4 = {0.f, 0.f, 0.f, 0.f};
    f32x4 acc[MF][4];
    #pragma unroll
    for (int i = 0; i < MF; i++)
        #pragma unroll
        for (int jj = 0; jj < 4; jj++) acc[i][jj] = zero4;

    stage(0, 0);
    const int nsteps = D_ / 32;
    for (int i = 0; i < nsteps; i++) {
        const int cur = i & 1;
        __syncthreads();
        if (i + 1 < nsteps) stage((i + 1) * 32, 1 - cur);

        bf16x8 af[MF], bfr[4];
        #pragma unroll
        for (int ii = 0; ii < MF; ii++) {
            const int ar_ = wm + ii * 16 + lrow;
            af[ii] = *(const bf16x8*)&As[cur][ar_ * 32 + ((kg ^ ((ar_ >> 1) & 3)) * 8)];
        }
        #pragma unroll
        for (int jj = 0; jj < 4; jj++) {
            const int wr_ = wn + jj * 16 + lrow;
            if (WF32) {
                const float4 wlo = *(const float4*)&Bs[cur][wr_ * 64 + (((2 * kg)     ^ (wr_ & 7)) * 8)];
                const float4 whi = *(const float4*)&Bs[cur][wr_ * 64 + (((2 * kg + 1) ^ (wr_ & 7)) * 8)];
                short t[8] = {f2bfs(wlo.x), f2bfs(wlo.y), f2bfs(wlo.z), f2bfs(wlo.w),
                              f2bfs(whi.x), f2bfs(whi.y), f2bfs(whi.z), f2bfs(whi.w)};
                bfr[jj] = *(const bf16x8*)t;
            } else {
                bfr[jj] = *(const bf16x8*)&Bs[cur][wr_ * 32 + ((kg ^ ((wr_ >> 1) & 3)) * 8)];
            }
        }
        #pragma unroll
        for (int ii = 0; ii < MF; ii++)
            #pragma unroll
            for (int jj = 0; jj < 4; jj++)
                acc[ii][jj] = mfma16(af[ii], bfr[jj], acc[ii][jj]);
    }

    #pragma unroll
    for (int jj = 0; jj < 4; jj++) {
        const int col = n0 + wn + jj * 16 + lrow;
        const float bv = Bp[col];
        #pragma unroll
        for (int i = 0; i < MF; i++) {
            #pragma unroll
            for (int r = 0; r < 4; r++) {
                const int row = m0 + wm + i * 16 + kg * 4 + r;
                float v = acc[i][jj][r] + bv;
                if (residMode) {
                    v += xin[(size_t)row * D_ + col] + rot_add(rf, row, col);
                }
                v = lclamp(v, 1.0e4f);
                if (Cf) Cf[(size_t)row * N + col] = v;
                else    Cb[(size_t)row * N + col] = __float2bfloat16(v);
            }
        }
    }
}

// ---------------------------------------------------------------------------
// Transpose V out of qkv: Vt[h][vd][l] = qkv[l][2*D + h*64 + vd]
// ---------------------------------------------------------------------------
__global__ __launch_bounds__(256) void transpose_v(
    const __hip_bfloat16* __restrict__ qkv,
    __hip_bfloat16* __restrict__ Vt)
{
    __shared__ __align__(16) short Ts[64 * 72];
    const int t = threadIdx.x;
    const int l0 = blockIdx.x * 64;
    const int h = blockIdx.y;
    #pragma unroll
    for (int p = 0; p < 2; p++) {
        const int idx = p * 256 + t;
        const int key = idx >> 3, part = idx & 7;
        *(uint4*)&Ts[key * 72 + part * 8] =
            *(const uint4*)&qkv[(size_t)(l0 + key) * TD + 2 * D_ + h * HD_ + part * 8];
    }
    __syncthreads();
    #pragma unroll
    for (int p = 0; p < 2; p++) {
        const int idx = p * 256 + t;
        const int vd = idx >> 3, part = idx & 7;
        short tmp[8];
        #pragma unroll
        for (int j = 0; j < 8; j++) tmp[j] = Ts[(part * 8 + j) * 72 + vd];
        *(uint4*)&Vt[(size_t)(h * HD_ + vd) * L_ + l0 + part * 8] = *(uint4*)tmp;
    }
}

// ---------------------------------------------------------------------------
// Flash attention v4 (round-4 proven version): fixed-max streaming softmax,
// XCD block swizzle, double-buffered global_load_lds K/V staging.
// ---------------------------------------------------------------------------
__global__ __launch_bounds__(256, 3) void attn_k(
    const __hip_bfloat16* __restrict__ qkv,
    const __hip_bfloat16* __restrict__ Vt,
    __hip_bfloat16* __restrict__ o,
    int Sw)
{
    const int tid  = threadIdx.x;
    const int lane = tid & 63;
    const int wave = tid >> 6;
    const int lrow = lane & 15;
    const int kg   = lane >> 4;

    int bx = blockIdx.x, by = blockIdx.y, bz = blockIdx.z;
    {
        const int gx = gridDim.x, gy = gridDim.y, gz = gridDim.z;
        const int nblk = gx * gy * gz;
        if ((nblk & 7) == 0) {
            const int lid = (blockIdx.z * gy + blockIdx.y) * gx + blockIdx.x;
            const int per = nblk >> 3;
            const int t = (lid & 7) * per + (lid >> 3);
            bx = t % gx;
            const int rest = t / gx;
            by = rest % gy;
            bz = rest / gy;
        }
    }
    const int h = by;
    const int wbase = bz * Sw;
    const int q0 = wbase + bx * 64 + wave * 16;

    const short* Kglb = reinterpret_cast<const short*>(qkv)
                        + (size_t)wbase * TD + D_ + h * HD_;
    const short* Vtglb = reinterpret_cast<const short*>(Vt)
                         + (size_t)h * HD_ * L_ + wbase;
    const __hip_bfloat16* Q = qkv + (size_t)q0 * TD + h * HD_;

    __shared__ __align__(16) short Ks[2][64 * 64];
    __shared__ __align__(16) short Vs[2][64 * 64];
    __shared__ __align__(16) short Ps[4][16 * 72];
    short* myP = &Ps[wave][0];

    const bf16x8 qf0 = *(const bf16x8*)&Q[(size_t)lrow * TD + kg * 8];
    const bf16x8 qf1 = *(const bf16x8*)&Q[(size_t)lrow * TD + 32 + kg * 8];

    const f32x4 zero4 = {0.f, 0.f, 0.f, 0.f};
    float lacc[4];
    f32x4 oacc[4];
    #pragma unroll
    for (int r = 0; r < 4; r++) lacc[r] = 0.f;
    #pragma unroll
    for (int t = 0; t < 4; t++) oacc[t] = zero4;

    auto stage = [&](int c, int buf) {
        const int s0 = (wave & 1) * 256;
        if (wave < 2) {
            #pragma unroll
            for (int j = 0; j < 4; j++) {
                const int s = s0 + j * 64 + lane;
                const int r = s >> 3;
                const int cb = (s & 7) ^ (r & 7);
                const short* src = Kglb + (size_t)(c + r) * TD + cb * 8;
                __builtin_amdgcn_global_load_lds(
                    (GVp*)src, (LVp*)&Ks[buf][(s0 + j * 64) * 8], 16, 0, 0);
            }
        } else {
            #pragma unroll
            for (int j = 0; j < 4; j++) {
                const int s = s0 + j * 64 + lane;
                const int r = s >> 3;
                const int cb = (s & 7) ^ (r & 7);
                const short* src = Vtglb + (size_t)r * L_ + c + cb * 8;
                __builtin_amdgcn_global_load_lds(
                    (GVp*)src, (LVp*)&Vs[buf][(s0 + j * 64) * 8], 16, 0, 0);
            }
        }
    };

    const int ntiles = Sw >> 6;
    stage(0, 0);

    // p = exp2(fma(s, 0.125*log2e, -16*log2e))
    const float SC = 0.18033688011112042f;
    const float MB = -23.083120654223414f;

    for (int i = 0; i < ntiles; i++) {
        const int cur = i & 1;
        __syncthreads();
        if (i + 1 < ntiles) stage((i + 1) << 6, 1 - cur);

        const short* Kl = Ks[cur];
        const short* Vl = Vs[cur];
        const int sw = lrow & 7;

        f32x4 s[4];
        #pragma unroll
        for (int kt = 0; kt < 4; kt++) {
            const int key = kt * 16 + lrow;
            bf16x8 k0 = *(const bf16x8*)&Kl[key * 64 + ((kg     ^ sw) * 8)];
            bf16x8 k1 = *(const bf16x8*)&Kl[key * 64 + (((kg+4) ^ sw) * 8)];
            f32x4 acc = zero4;
            acc = mfma16(qf0, k0, acc);
            acc = mfma16(qf1, k1, acc);
            s[kt] = acc;
        }

        asm volatile("" ::: "memory");
        #pragma unroll
        for (int kt = 0; kt < 4; kt++) {
            #pragma unroll
            for (int r = 0; r < 4; r++) {
                const float p = exp2f(fmaf(s[kt][r], SC, MB));
                lacc[r] += p;
                myP[(kg * 4 + r) * 72 + kt * 16 + lrow] = f2bfs(p);
            }
        }
        asm volatile("s_waitcnt lgkmcnt(0)" ::: "memory");
        const bf16x8 pf0 = *(const bf16x8*)&myP[lrow * 72 + kg * 8];
        const bf16x8 pf1 = *(const bf16x8*)&myP[lrow * 72 + 32 + kg * 8];

        #pragma unroll
        for (int t = 0; t < 4; t++) {
            const int vd = t * 16 + lrow;
            bf16x8 v0 = *(const bf16x8*)&Vl[vd * 64 + ((kg     ^ sw) * 8)];
            bf16x8 v1 = *(const bf16x8*)&Vl[vd * 64 + (((kg+4) ^ sw) * 8)];
            oacc[t] = mfma16(pf0, v0, oacc[t]);
            oacc[t] = mfma16(pf1, v1, oacc[t]);
        }
    }

    #pragma unroll
    for (int off = 1; off < 16; off <<= 1)
        #pragma unroll
        for (int r = 0; r < 4; r++)
            lacc[r] += __shfl_xor(lacc[r], off, 64);

    #pragma unroll
    for (int t = 0; t < 4; t++) {
        #pragma unroll
        for (int r = 0; r < 4; r++) {
            const int row = q0 + kg * 4 + r;
            const int col = h * HD_ + t * 16 + lrow;
            o[(size_t)row * D_ + col] =
                __float2bfloat16(lclamp(oacc[t][r] / lacc[r], 1.0e4f));
        }
    }
}

// ---------------------------------------------------------------------------
extern "C" void kernel_launch(void* const* d_in, const int* in_sizes, int n_in,
                              void* d_out, int out_size, void* d_ws, size_t ws_size,
                              hipStream_t stream)
{
    const float* x   = (const float*)d_in[0];
    const float* rf  = (const float*)d_in[1];
    const float* wwi = (const float*)d_in[2];
    const float* wbi = (const float*)d_in[3];
    const float* wwo = (const float*)d_in[4];
    const float* wbo = (const float*)d_in[5];
    const float* fwi = (const float*)d_in[6];
    const float* fbi = (const float*)d_in[7];
    const float* fwo = (const float*)d_in[8];
    const float* fbo = (const float*)d_in[9];

    char* ws = (char*)d_ws;
    __hip_bfloat16* qkv = (__hip_bfloat16*)(ws);                 // [L,3D] 24 MiB
    __hip_bfloat16* ob  = (__hip_bfloat16*)(ws + (24u << 20));   // [L,D]   8 MiB
    __hip_bfloat16* xsc = (__hip_bfloat16*)d_out;                // [L,D] bf16 scratch
    __hip_bfloat16* Vt  = (__hip_bfloat16*)d_out;                // [H,HD,L] bf16

    const size_t MB1 = 1u << 20;
    const int bw = (ws_size >= 104 * MB1) ? 1 : 0;

    __hip_bfloat16* wwib = (__hip_bfloat16*)(ws + 32 * MB1);
    __hip_bfloat16* wwob = (__hip_bfloat16*)(ws + 80 * MB1);
    __hip_bfloat16* fwib = (__hip_bfloat16*)(ws + 96 * MB1);
    __hip_bfloat16* fwob = (__hip_bfloat16*)(ws + 102 * MB1);
    if (bw) {
        wcvt_all<<<dim3(36864), 256, 0, stream>>>(
            wwi, wwo, fwi, fwo, wwib, wwob, fwib, fwob);
    }

    // 1. rotary add -> x1 (bf16)
    rotary_k<<<dim3(L_ * D_ / 256), 256, 0, stream>>>(x, rf, xsc);

    // 2. per-window qkv = x1 @ win_w_in^T + win_b_in   (8-phase 256^2)
    if (bw) gemm8<<<dim3(TD / 256, L_ / 256), 512, 0, stream>>>(
        xsc, wwib, wbi, qkv, TD, TD * D_, TD);
    else    gemm_u<1, 128><<<dim3(TD / 128, L_ / 128), 256, 0, stream>>>(
        xsc, wwi,  wbi, nullptr, nullptr, 0, qkv, nullptr, TD, TD * D_, TD);

    // 2b. V transpose
    transpose_v<<<dim3(L_ / 64, H_), 256, 0, stream>>>(qkv, Vt);

    // 3. windowed attention (Sw = 512)
    attn_k<<<dim3(WIN_ / 64, H_, NW_), 256, 0, stream>>>(qkv, Vt, ob, WIN_);

    // 4. x2 = (x + rotary, exact fp32) + o @ win_w_out^T + win_b_out
    if (bw) gemm_u<0, 64><<<dim3(D_ / 128, L_ / 64), 256, 0, stream>>>(
        ob, wwob, wbo, x, rf, 1, xsc, nullptr, D_, D_ * D_, D_);
    else    gemm_u<1, 128><<<dim3(D_ / 128, L_ / 128), 256, 0, stream>>>(
        ob, wwo,  wbo, x, rf, 1, xsc, nullptr, D_, D_ * D_, D_);

    // 5. final qkv = x2 @ fin_w_in^T + fin_b_in   (8-phase 256^2)
    if (bw) gemm8<<<dim3(TD / 256, L_ / 256), 512, 0, stream>>>(
        xsc, fwib, fbi, qkv, TD, 0, 0);
    else    gemm_u<1, 128><<<dim3(TD / 128, L_ / 128), 256, 0, stream>>>(
        xsc, fwi,  fbi, nullptr, nullptr, 0, qkv, nullptr, TD, 0, 0);

    // 5b. V transpose
    transpose_v<<<dim3(L_ / 64, H_), 256, 0, stream>>>(qkv, Vt);

    // 6. global attention (Sw = 4096)
    attn_k<<<dim3(L_ / 64, H_, 1), 256, 0, stream>>>(qkv, Vt, ob, L_);

    // 7. out = o @ fin_w_out^T + fin_b_out  -> d_out (fp32, final)
    if (bw) gemm_u<0, 64><<<dim3(D_ / 128, L_ / 64), 256, 0, stream>>>(
        ob, fwob, fbo, nullptr, nullptr, 0, nullptr, (float*)d_out, D_, 0, 0);
    else    gemm_u<1, 128><<<dim3(D_ / 128, L_ / 128), 256, 0, stream>>>(
        ob, fwo,  fbo, nullptr, nullptr, 0, nullptr, (float*)d_out, D_, 0, 0);
}